// Round 6
// baseline (824.089 us; speedup 1.0000x reference)
//
#include <hip/hip_runtime.h>

#define EPS 1e-5f

typedef __attribute__((ext_vector_type(8))) short bf16x8;
typedef __attribute__((ext_vector_type(4))) float f32x4;

__device__ __forceinline__ unsigned short f2bf(float f) {
    unsigned u = __float_as_uint(f);
    u += 0x7fffu + ((u >> 16) & 1u);
    return (unsigned short)(u >> 16);
}
__device__ __forceinline__ float bf2f(unsigned short s) {
    return __uint_as_float(((unsigned)s) << 16);
}

// ---------------------------------------------------------------------------
// Edge-index dtype detection: JAX may emit int32 (x64 disabled) or int64.
__global__ void k_detect(const int* __restrict__ ei, int* __restrict__ flag) {
    if (blockIdx.x == 0 && threadIdx.x == 0) {
        int is64 = 1;
        for (int k = 0; k < 16; ++k) is64 &= (ei[2 * k + 1] == 0) ? 1 : 0;
        *flag = is64;
    }
}

__device__ __forceinline__ void load_edge(const int* __restrict__ ei, int E, int e,
                                          int f, int& s, int& d) {
    if (f) { s = ei[2 * e]; d = ei[2 * E + 2 * e]; }
    else   { s = ei[e];     d = ei[E + e]; }
}

// ---------------------------------------------------------------------------
// CSR build: histogram -> exclusive scan (3 kernels) -> fill
__global__ void k_hist(const int* __restrict__ ei, const int* __restrict__ flag,
                       int E, int* __restrict__ cnt) {
    int e = blockIdx.x * blockDim.x + threadIdx.x;
    if (e >= E) return;
    int f = *flag;
    int d = f ? ei[2 * E + 2 * e] : ei[E + e];
    atomicAdd(&cnt[d], 1);
}

__device__ __forceinline__ int block_incl_scan(int v, int tid, int* total) {
    __shared__ int wsum[4];
    __shared__ int tot;
#pragma unroll
    for (int o = 1; o < 64; o <<= 1) {
        int u = __shfl_up(v, o, 64);
        if ((tid & 63) >= o) v += u;
    }
    if ((tid & 63) == 63) wsum[tid >> 6] = v;
    __syncthreads();
    int w = tid >> 6, add = 0;
    if (w > 0) add += wsum[0];
    if (w > 1) add += wsum[1];
    if (w > 2) add += wsum[2];
    v += add;
    if (tid == 255) tot = v;
    __syncthreads();
    *total = tot;
    __syncthreads();
    return v;
}

__global__ __launch_bounds__(256) void k_scanA(const int* __restrict__ cnt, int n,
                                               int* __restrict__ bsums) {
    int tid = threadIdx.x;
    int idx = blockIdx.x * 1024 + tid * 4;
    int s = 0;
#pragma unroll
    for (int k = 0; k < 4; ++k) { int i = idx + k; if (i < n) s += cnt[i]; }
#pragma unroll
    for (int o = 32; o > 0; o >>= 1) s += __shfl_xor(s, o, 64);
    __shared__ int ws[4];
    if ((tid & 63) == 0) ws[tid >> 6] = s;
    __syncthreads();
    if (tid == 0) bsums[blockIdx.x] = ws[0] + ws[1] + ws[2] + ws[3];
}

__global__ __launch_bounds__(256) void k_scanB(int* __restrict__ bsums, int nb,
                                               int* __restrict__ rowptr, int N) {
    int tid = threadIdx.x;
    __shared__ int sh_carry;
    if (tid == 0) sh_carry = 0;
    __syncthreads();
    int niter = (nb + 255) / 256;
    for (int it = 0; it < niter; ++it) {
        int i = it * 256 + tid;
        int v = (i < nb) ? bsums[i] : 0;
        int tot;
        int inc = block_incl_scan(v, tid, &tot);
        int carry = sh_carry;
        if (i < nb) bsums[i] = carry + inc - v;
        __syncthreads();
        if (tid == 0) sh_carry = carry + tot;
        __syncthreads();
    }
    if (tid == 0) rowptr[N] = sh_carry;
}

__global__ __launch_bounds__(256) void k_scanC(int* __restrict__ cnt_rowptr, int n,
                                               const int* __restrict__ bsums,
                                               int* __restrict__ cursor) {
    int tid = threadIdx.x;
    int idx = blockIdx.x * 1024 + tid * 4;
    int v[4]; int s = 0;
#pragma unroll
    for (int k = 0; k < 4; ++k) { int i = idx + k; v[k] = (i < n) ? cnt_rowptr[i] : 0; s += v[k]; }
    int tot;
    int inc = block_incl_scan(s, tid, &tot);
    int off = bsums[blockIdx.x] + inc - s;
#pragma unroll
    for (int k = 0; k < 4; ++k) {
        int i = idx + k;
        if (i < n) { cnt_rowptr[i] = off; cursor[i] = off; off += v[k]; }
    }
}

__global__ void k_fill(const int* __restrict__ ei, const int* __restrict__ flag, int E,
                       int* __restrict__ cursor, int* __restrict__ csr) {
    int e = blockIdx.x * blockDim.x + threadIdx.x;
    if (e >= E) return;
    int f = *flag, s, d;
    load_edge(ei, E, e, f, s, d);
    int pos = atomicAdd(&cursor[d], 1);
    csr[pos] = s;
}

// ---------------------------------------------------------------------------
__global__ void k_gather1(const float* __restrict__ x, const int* __restrict__ rowptr,
                          const int* __restrict__ csr, float* __restrict__ agg1, int n) {
    int i = blockIdx.x * blockDim.x + threadIdx.x;
    if (i >= n) return;
    int r0 = rowptr[i], r1 = rowptr[i + 1];
    float s0 = 0.f, s1 = 0.f;
    for (int j = r0; j < r1; ++j) {
        int s = csr[j];
        s0 += x[2 * s]; s1 += x[2 * s + 1];
    }
    float inv = 1.f / fmaxf((float)(r1 - r0), 1.f);
    agg1[2 * i] = s0 * inv;
    agg1[2 * i + 1] = s1 * inv;
}

// ---------------------------------------------------------------------------
// Layer-1 dense (K=2): h1 = agg1@W1l + b1 + x@W1r -> bf16 store.
// BN stats accumulated on the TRUNCATED value (self-consistent with readers).
__global__ __launch_bounds__(256) void k_dense1(
    const float* __restrict__ x, const float* __restrict__ agg1,
    const float* __restrict__ W1l, const float* __restrict__ b1,
    const float* __restrict__ W1r,
    unsigned short* __restrict__ h1b, float* __restrict__ stats, int n) {
    int tid = threadIdx.x, c = tid & 63, w = tid >> 6;
    float wl0 = W1l[c], wl1 = W1l[64 + c];
    float wr0 = W1r[c], wr1 = W1r[64 + c];
    float bb = b1[c];
    float ls = 0.f, lq = 0.f;
    for (int i = blockIdx.x * 4 + w; i < n; i += gridDim.x * 4) {
        float a0 = agg1[2 * i], a1 = agg1[2 * i + 1];
        float x0 = x[2 * i], x1v = x[2 * i + 1];
        float h = fmaf(a0, wl0, fmaf(a1, wl1, fmaf(x0, wr0, fmaf(x1v, wr1, bb))));
        unsigned short hb = f2bf(h);
        h1b[(size_t)i * 64 + c] = hb;
        float hf = bf2f(hb);
        ls += hf; lq += hf * hf;
    }
    __shared__ float red[256];
    red[tid] = ls; __syncthreads();
    if (tid < 64) atomicAdd(&stats[tid], red[tid] + red[tid + 64] + red[tid + 128] + red[tid + 192]);
    __syncthreads();
    red[tid] = lq; __syncthreads();
    if (tid < 64) atomicAdd(&stats[64 + tid], red[tid] + red[tid + 64] + red[tid + 128] + red[tid + 192]);
}

// ---------------------------------------------------------------------------
__global__ void k_bnfin(const float* __restrict__ stats, const float* __restrict__ g,
                        const float* __restrict__ be, float* __restrict__ coef, float invN) {
    int c = threadIdx.x;
    float m = stats[c] * invN;
    float var = stats[64 + c] * invN - m * m;
    float a = g[c] * rsqrtf(var + EPS);
    coef[c] = a;
    coef[64 + c] = be[c] - m * a;
}

// ---------------------------------------------------------------------------
// FUSED layer 2: per wave, gather 16 node rows (mean of relu(bn1(h1[src])))
// into wave-private LDS, then MFMA against W (staged in LDS), write the
// 16x64 bf16 tile via LDS out-stage -> fully coalesced 2KB global stores.
// No agg2 intermediate in HBM; no __syncthreads in the main loop (all
// staging is wave-private; explicit lgkmcnt(0) fences order ds_write->ds_read
// within the wave).
#define LROW 72  // LDS row stride in shorts (144 B: 16B-aligned, bank-spread)

__global__ __launch_bounds__(256) void k_layer2(
    const unsigned short* __restrict__ h1b, const int* __restrict__ rowptr,
    const int* __restrict__ csr, const float* __restrict__ coef1,
    const float* __restrict__ W2l, const float* __restrict__ b2,
    const float* __restrict__ W2r,
    unsigned short* __restrict__ h2b, float* __restrict__ stats, int n) {
    __shared__ __align__(16) unsigned short lds_w[16 * 64 * 8];   // 16 KB W frags
    __shared__ __align__(16) unsigned short lds_a[4][16 * LROW];  // A-stage / wave
    __shared__ __align__(16) unsigned short lds_o[4][16 * LROW];  // out-stage / wave
    int tid = threadIdx.x, w = tid >> 6, l = tid & 63, ln = l & 15, kg = l >> 4;

    // Stage W fragments (as round 5: frag=(k>>5)*4+(c>>4), lane, j=k&7)
    for (int idx = tid; idx < 4096; idx += 256) {
        int k = idx >> 6, c = idx & 63;
        unsigned short wl = f2bf(W2l[idx]);
        unsigned short wr = f2bf(W2r[idx]);
        int lane = ((k >> 3) & 3) * 16 + (c & 15);
        int slotl = (((k >> 5) * 4 + (c >> 4)) * 64 + lane) * 8 + (k & 7);
        int slotr = ((((k + 64) >> 5) * 4 + (c >> 4)) * 64 + lane) * 8 + (k & 7);
        lds_w[slotl] = wl;
        lds_w[slotr] = wr;
    }
    __syncthreads();

    float ga = coef1[l], gb = coef1[64 + l];   // gather-side BN (lane = channel)
    float bb[4];
#pragma unroll
    for (int cs = 0; cs < 4; ++cs) bb[cs] = b2[cs * 16 + ln];
    float c1a[16], c1b[16];                    // self-row BN per k-slice
#pragma unroll
    for (int j = 0; j < 8; ++j) {
        c1a[j]     = coef1[kg * 8 + j];       c1b[j]     = coef1[64 + kg * 8 + j];
        c1a[8 + j] = coef1[32 + kg * 8 + j];  c1b[8 + j] = coef1[96 + kg * 8 + j];
    }

    unsigned short* As = lds_a[w];
    unsigned short* Os = lds_o[w];
    const bf16x8* wfrag = (const bf16x8*)lds_w;
    float ls[4] = {0.f, 0.f, 0.f, 0.f};
    float lq[4] = {0.f, 0.f, 0.f, 0.f};

    int ngrp = (n + 63) >> 6;
    for (int g = blockIdx.x; g < ngrp; g += gridDim.x) {
        int base = (g << 6) + w * 16;   // this wave's 16 nodes
        // ---- phase 1: gather (lane = channel, 128B coalesced per neighbor)
        for (int ii = 0; ii < 16; ++ii) {
            int i = base + ii;
            float s = 0.f;
            if (i < n) {
                int r0 = rowptr[i], r1 = rowptr[i + 1];
                int j = r0;
                for (; j + 1 < r1; j += 2) {
                    float v0 = bf2f(h1b[(size_t)csr[j] * 64 + l]);
                    float v1 = bf2f(h1b[(size_t)csr[j + 1] * 64 + l]);
                    s += fmaxf(0.f, fmaf(v0, ga, gb)) + fmaxf(0.f, fmaf(v1, ga, gb));
                }
                if (j < r1) {
                    float v0 = bf2f(h1b[(size_t)csr[j] * 64 + l]);
                    s += fmaxf(0.f, fmaf(v0, ga, gb));
                }
                s *= 1.f / fmaxf((float)(r1 - r0), 1.f);
            }
            As[ii * LROW + l] = f2bf(s);
        }
        asm volatile("s_waitcnt lgkmcnt(0)" ::: "memory");  // drain ds_writes

        // ---- phase 2: MFMA (A from LDS + self rows from global)
        const unsigned short* arow = As + ln * LROW + kg * 8;
        bf16x8 a0 = *(const bf16x8*)arow;
        bf16x8 a1 = *(const bf16x8*)(arow + 32);
        int row = base + ln;
        int rr = (row < n) ? row : (n - 1);
        const unsigned short* xr = h1b + (size_t)rr * 64 + kg * 8;
        bf16x8 r2 = *(const bf16x8*)xr;
        bf16x8 r3 = *(const bf16x8*)(xr + 32);
        bf16x8 a2, a3;
#pragma unroll
        for (int j = 0; j < 8; ++j) {
            float f2_ = bf2f((unsigned short)r2[j]);
            float f3_ = bf2f((unsigned short)r3[j]);
            a2[j] = (short)f2bf(fmaxf(0.f, fmaf(f2_, c1a[j], c1b[j])));
            a3[j] = (short)f2bf(fmaxf(0.f, fmaf(f3_, c1a[8 + j], c1b[8 + j])));
        }
        f32x4 acc[4];
#pragma unroll
        for (int cs = 0; cs < 4; ++cs) acc[cs] = (f32x4){0.f, 0.f, 0.f, 0.f};
#pragma unroll
        for (int cs = 0; cs < 4; ++cs) {
            acc[cs] = __builtin_amdgcn_mfma_f32_16x16x32_bf16(a0, wfrag[(0 * 4 + cs) * 64 + l], acc[cs], 0, 0, 0);
            acc[cs] = __builtin_amdgcn_mfma_f32_16x16x32_bf16(a1, wfrag[(1 * 4 + cs) * 64 + l], acc[cs], 0, 0, 0);
            acc[cs] = __builtin_amdgcn_mfma_f32_16x16x32_bf16(a2, wfrag[(2 * 4 + cs) * 64 + l], acc[cs], 0, 0, 0);
            acc[cs] = __builtin_amdgcn_mfma_f32_16x16x32_bf16(a3, wfrag[(3 * 4 + cs) * 64 + l], acc[cs], 0, 0, 0);
        }
        // ---- epilogue: bias + bf16 + stats, stage tile in LDS
#pragma unroll
        for (int cs = 0; cs < 4; ++cs) {
#pragma unroll
            for (int r = 0; r < 4; ++r) {
                int node = base + kg * 4 + r;
                float h = acc[cs][r] + bb[cs];
                unsigned short hb = f2bf(h);
                Os[(kg * 4 + r) * LROW + cs * 16 + ln] = hb;
                if (node < n) {
                    float hf = bf2f(hb);
                    ls[cs] += hf; lq[cs] += hf * hf;
                }
            }
        }
        asm volatile("s_waitcnt lgkmcnt(0)" ::: "memory");  // drain ds_writes

        // ---- coalesced readout: 16 rows x 128B = 2KB contiguous per wave
        int orow = l >> 2, oc = (l & 3) * 16;
        const bf16x8* op = (const bf16x8*)(Os + orow * LROW + oc);
        bf16x8 o0 = op[0];
        bf16x8 o1 = op[1];
        if (base + orow < n) {
            bf16x8* dst = (bf16x8*)(h2b + (size_t)(base + orow) * 64 + oc);
            dst[0] = o0;
            dst[1] = o1;
        }
    }
    // ---- BN2 stats: lanes {l, l^16, l^32, l^48} share channel cs*16+ln
#pragma unroll
    for (int cs = 0; cs < 4; ++cs) {
        float s = ls[cs], q = lq[cs];
        s += __shfl_xor(s, 16, 64); s += __shfl_xor(s, 32, 64);
        q += __shfl_xor(q, 16, 64); q += __shfl_xor(q, 32, 64);
        if (kg == 0) {
            atomicAdd(&stats[cs * 16 + ln], s);
            atomicAdd(&stats[64 + cs * 16 + ln], q);
        }
    }
}

// ---------------------------------------------------------------------------
// Finalize: x2 = relu(bn2(h2)) + relu(bn1(h1)); t = x2.W3l; v = x2.W3r.
// 8 nodes per wave -> 16 independent 128B loads in flight.
__global__ __launch_bounds__(256) void k_finalize(
    const unsigned short* __restrict__ h2b, const unsigned short* __restrict__ h1b,
    const float* __restrict__ coef1, const float* __restrict__ coef2,
    const float* __restrict__ W3l, const float* __restrict__ W3r,
    float* __restrict__ tb, float* __restrict__ vb, int n) {
    int tid = threadIdx.x, c = tid & 63, w = tid >> 6;
    int i0 = (blockIdx.x * 4 + w) * 8;
    if (i0 >= n) return;
    float a1 = coef1[c], b1 = coef1[64 + c];
    float a2 = coef2[c], b2 = coef2[64 + c];
    float wl = W3l[c], wr = W3r[c];
    float tv[8], vv[8];
#pragma unroll
    for (int q = 0; q < 8; ++q) {
        int i = i0 + q; int ic = (i < n) ? i : (n - 1);
        float h1v = bf2f(h1b[(size_t)ic * 64 + c]);
        float h2v = bf2f(h2b[(size_t)ic * 64 + c]);
        float x1v = fmaxf(0.f, fmaf(h1v, a1, b1));
        float x2v = fmaxf(0.f, fmaf(h2v, a2, b2)) + x1v;
        tv[q] = x2v * wl; vv[q] = x2v * wr;
    }
#pragma unroll
    for (int q = 0; q < 8; ++q) {
        float t = tv[q], v = vv[q];
#pragma unroll
        for (int o = 32; o > 0; o >>= 1) {
            t += __shfl_xor(t, o, 64);
            v += __shfl_xor(v, o, 64);
        }
        if (c == 0 && i0 + q < n) { tb[i0 + q] = t; vb[i0 + q] = v; }
    }
}

// ---------------------------------------------------------------------------
__global__ void k_gather3(const float* __restrict__ tb, const float* __restrict__ vb,
                          const int* __restrict__ rowptr, const int* __restrict__ csr,
                          const float* __restrict__ b3, float* __restrict__ out, int n) {
    int i = blockIdx.x * blockDim.x + threadIdx.x;
    if (i >= n) return;
    int r0 = rowptr[i], r1 = rowptr[i + 1];
    float s = 0.f;
    for (int j = r0; j < r1; ++j) s += tb[csr[j]];
    float inv = 1.f / fmaxf((float)(r1 - r0), 1.f);
    out[i] = fmaf(s, inv, b3[0] + vb[i]);
}

// ---------------------------------------------------------------------------
// Workspace (4B units, N=500k, E=1.25M; cap 256 MiB = 67,108,864 units):
//   h1b 32N + h2b 32N + R 2N + rowptr N+1 + csr E + bsums/stats/coef/flag
//   = ~34.8M units = 139 MB (safe)
extern "C" void kernel_launch(void* const* d_in, const int* in_sizes, int n_in,
                              void* d_out, int out_size, void* d_ws, size_t ws_size,
                              hipStream_t stream) {
    const float* x   = (const float*)d_in[0];
    const int*   ei  = (const int*)d_in[1];
    const float* W1l = (const float*)d_in[2];
    const float* b1  = (const float*)d_in[3];
    const float* W1r = (const float*)d_in[4];
    const float* g1  = (const float*)d_in[5];
    const float* be1 = (const float*)d_in[6];
    const float* W2l = (const float*)d_in[7];
    const float* b2  = (const float*)d_in[8];
    const float* W2r = (const float*)d_in[9];
    const float* g2  = (const float*)d_in[10];
    const float* be2 = (const float*)d_in[11];
    const float* W3l = (const float*)d_in[12];
    const float* b3  = (const float*)d_in[13];
    const float* W3r = (const float*)d_in[14];

    int N = in_sizes[0] / 2;
    int E = in_sizes[1] / 2;

    float* ws   = (float*)d_ws;
    size_t nn   = (size_t)N;
    unsigned short* h1b = (unsigned short*)ws;             // 32N units
    unsigned short* h2b = (unsigned short*)(ws + 32 * nn); // 32N units
    float* R     = ws + 64 * nn;           // 2N time-shared region
    int*   cursor = (int*)R;               //   phase 1: CSR build (N+1 ints)
    float* agg1   = R;                     //   phase 2: layer-1 agg (2N f32)
    float* tb     = R;                     //   phase 3: layer-3 t (N f32)
    float* vb     = R + nn;                //   phase 3: layer-3 v (N f32)
    int*   rowptr = (int*)(ws + 66 * nn);  // N+1 (doubles as histogram cnt)
    int*   csr    = rowptr + (N + 1);      // E
    int*   bsums  = csr + E;               // 2048
    float* stats  = (float*)(bsums + 2048);// 256: s1,q1 | s2,q2
    float* coef   = stats + 256;           // 256: a1,b1 | a2,b2
    int*   flag   = (int*)(coef + 256);    // 64 (padded)

    hipMemsetAsync(rowptr, 0, (size_t)(N + 1) * sizeof(int), stream);
    hipMemsetAsync(stats, 0, 256 * sizeof(float), stream);

    k_detect<<<1, 1, 0, stream>>>(ei, flag);

    int ge = (E + 255) / 256;
    int nb = (N + 1023) / 1024;
    k_hist<<<ge, 256, 0, stream>>>(ei, flag, E, rowptr);
    k_scanA<<<nb, 256, 0, stream>>>(rowptr, N, bsums);
    k_scanB<<<1, 256, 0, stream>>>(bsums, nb, rowptr, N);
    k_scanC<<<nb, 256, 0, stream>>>(rowptr, N, bsums, cursor);
    k_fill<<<ge, 256, 0, stream>>>(ei, flag, E, cursor, csr);
    // cursor dead; R becomes agg1

    k_gather1<<<(N + 255) / 256, 256, 0, stream>>>(x, rowptr, csr, agg1, N);
    k_dense1<<<1024, 256, 0, stream>>>(x, agg1, W1l, b1, W1r, h1b, stats, N);
    k_bnfin<<<1, 64, 0, stream>>>(stats, g1, be1, coef, 1.0f / (float)N);
    // agg1 dead after dense1

    k_layer2<<<2048, 256, 0, stream>>>(h1b, rowptr, csr, coef, W2l, b2, W2r,
                                       h2b, stats + 128, N);
    k_bnfin<<<1, 64, 0, stream>>>(stats + 128, g2, be2, coef + 128, 1.0f / (float)N);

    // R becomes tb/vb
    k_finalize<<<(N + 31) / 32, 256, 0, stream>>>(h2b, h1b, coef, coef + 128,
                                                  W3l, W3r, tb, vb, N);
    k_gather3<<<(N + 255) / 256, 256, 0, stream>>>(tb, vb, rowptr, csr, b3, (float*)d_out, N);
}

// Round 7
// 693.032 us; speedup vs baseline: 1.1891x; 1.1891x over previous
//
#include <hip/hip_runtime.h>

#define EPS 1e-5f

typedef __attribute__((ext_vector_type(8))) short bf16x8;
typedef __attribute__((ext_vector_type(4))) float f32x4;

__device__ __forceinline__ unsigned short f2bf(float f) {
    unsigned u = __float_as_uint(f);
    u += 0x7fffu + ((u >> 16) & 1u);
    return (unsigned short)(u >> 16);
}
__device__ __forceinline__ float bf2f(unsigned short s) {
    return __uint_as_float(((unsigned)s) << 16);
}

// ---------------------------------------------------------------------------
// Edge-index dtype detection: JAX may emit int32 (x64 disabled) or int64.
__global__ void k_detect(const int* __restrict__ ei, int* __restrict__ flag) {
    if (blockIdx.x == 0 && threadIdx.x == 0) {
        int is64 = 1;
        for (int k = 0; k < 16; ++k) is64 &= (ei[2 * k + 1] == 0) ? 1 : 0;
        *flag = is64;
    }
}

__device__ __forceinline__ void load_edge(const int* __restrict__ ei, int E, int e,
                                          int f, int& s, int& d) {
    if (f) { s = ei[2 * e]; d = ei[2 * E + 2 * e]; }
    else   { s = ei[e];     d = ei[E + e]; }
}

// ---------------------------------------------------------------------------
// CSR build: histogram -> exclusive scan (3 kernels) -> fill
__global__ void k_hist(const int* __restrict__ ei, const int* __restrict__ flag,
                       int E, int* __restrict__ cnt) {
    int e = blockIdx.x * blockDim.x + threadIdx.x;
    if (e >= E) return;
    int f = *flag;
    int d = f ? ei[2 * E + 2 * e] : ei[E + e];
    atomicAdd(&cnt[d], 1);
}

__device__ __forceinline__ int block_incl_scan(int v, int tid, int* total) {
    __shared__ int wsum[4];
    __shared__ int tot;
#pragma unroll
    for (int o = 1; o < 64; o <<= 1) {
        int u = __shfl_up(v, o, 64);
        if ((tid & 63) >= o) v += u;
    }
    if ((tid & 63) == 63) wsum[tid >> 6] = v;
    __syncthreads();
    int w = tid >> 6, add = 0;
    if (w > 0) add += wsum[0];
    if (w > 1) add += wsum[1];
    if (w > 2) add += wsum[2];
    v += add;
    if (tid == 255) tot = v;
    __syncthreads();
    *total = tot;
    __syncthreads();
    return v;
}

__global__ __launch_bounds__(256) void k_scanA(const int* __restrict__ cnt, int n,
                                               int* __restrict__ bsums) {
    int tid = threadIdx.x;
    int idx = blockIdx.x * 1024 + tid * 4;
    int s = 0;
#pragma unroll
    for (int k = 0; k < 4; ++k) { int i = idx + k; if (i < n) s += cnt[i]; }
#pragma unroll
    for (int o = 32; o > 0; o >>= 1) s += __shfl_xor(s, o, 64);
    __shared__ int ws[4];
    if ((tid & 63) == 0) ws[tid >> 6] = s;
    __syncthreads();
    if (tid == 0) bsums[blockIdx.x] = ws[0] + ws[1] + ws[2] + ws[3];
}

__global__ __launch_bounds__(256) void k_scanB(int* __restrict__ bsums, int nb,
                                               int* __restrict__ rowptr, int N) {
    int tid = threadIdx.x;
    __shared__ int sh_carry;
    if (tid == 0) sh_carry = 0;
    __syncthreads();
    int niter = (nb + 255) / 256;
    for (int it = 0; it < niter; ++it) {
        int i = it * 256 + tid;
        int v = (i < nb) ? bsums[i] : 0;
        int tot;
        int inc = block_incl_scan(v, tid, &tot);
        int carry = sh_carry;
        if (i < nb) bsums[i] = carry + inc - v;
        __syncthreads();
        if (tid == 0) sh_carry = carry + tot;
        __syncthreads();
    }
    if (tid == 0) rowptr[N] = sh_carry;
}

__global__ __launch_bounds__(256) void k_scanC(int* __restrict__ cnt_rowptr, int n,
                                               const int* __restrict__ bsums,
                                               int* __restrict__ cursor) {
    int tid = threadIdx.x;
    int idx = blockIdx.x * 1024 + tid * 4;
    int v[4]; int s = 0;
#pragma unroll
    for (int k = 0; k < 4; ++k) { int i = idx + k; v[k] = (i < n) ? cnt_rowptr[i] : 0; s += v[k]; }
    int tot;
    int inc = block_incl_scan(s, tid, &tot);
    int off = bsums[blockIdx.x] + inc - s;
#pragma unroll
    for (int k = 0; k < 4; ++k) {
        int i = idx + k;
        if (i < n) { cnt_rowptr[i] = off; cursor[i] = off; off += v[k]; }
    }
}

__global__ void k_fill(const int* __restrict__ ei, const int* __restrict__ flag, int E,
                       int* __restrict__ cursor, int* __restrict__ csr) {
    int e = blockIdx.x * blockDim.x + threadIdx.x;
    if (e >= E) return;
    int f = *flag, s, d;
    load_edge(ei, E, e, f, s, d);
    int pos = atomicAdd(&cursor[d], 1);
    csr[pos] = s;
}

// ---------------------------------------------------------------------------
__global__ void k_gather1(const float* __restrict__ x, const int* __restrict__ rowptr,
                          const int* __restrict__ csr, float* __restrict__ agg1, int n) {
    int i = blockIdx.x * blockDim.x + threadIdx.x;
    if (i >= n) return;
    int r0 = rowptr[i], r1 = rowptr[i + 1];
    float s0 = 0.f, s1 = 0.f;
    for (int j = r0; j < r1; ++j) {
        int s = csr[j];
        s0 += x[2 * s]; s1 += x[2 * s + 1];
    }
    float inv = 1.f / fmaxf((float)(r1 - r0), 1.f);
    agg1[2 * i] = s0 * inv;
    agg1[2 * i + 1] = s1 * inv;
}

// ---------------------------------------------------------------------------
// Layer-1 dense (K=2): h1 = agg1@W1l + b1 + x@W1r -> bf16 store.
// BN stats accumulated on the TRUNCATED value (self-consistent with readers).
__global__ __launch_bounds__(256) void k_dense1(
    const float* __restrict__ x, const float* __restrict__ agg1,
    const float* __restrict__ W1l, const float* __restrict__ b1,
    const float* __restrict__ W1r,
    unsigned short* __restrict__ h1b, float* __restrict__ stats, int n) {
    int tid = threadIdx.x, c = tid & 63, w = tid >> 6;
    float wl0 = W1l[c], wl1 = W1l[64 + c];
    float wr0 = W1r[c], wr1 = W1r[64 + c];
    float bb = b1[c];
    float ls = 0.f, lq = 0.f;
    for (int i = blockIdx.x * 4 + w; i < n; i += gridDim.x * 4) {
        float a0 = agg1[2 * i], a1 = agg1[2 * i + 1];
        float x0 = x[2 * i], x1v = x[2 * i + 1];
        float h = fmaf(a0, wl0, fmaf(a1, wl1, fmaf(x0, wr0, fmaf(x1v, wr1, bb))));
        unsigned short hb = f2bf(h);
        h1b[(size_t)i * 64 + c] = hb;
        float hf = bf2f(hb);
        ls += hf; lq += hf * hf;
    }
    __shared__ float red[256];
    red[tid] = ls; __syncthreads();
    if (tid < 64) atomicAdd(&stats[tid], red[tid] + red[tid + 64] + red[tid + 128] + red[tid + 192]);
    __syncthreads();
    red[tid] = lq; __syncthreads();
    if (tid < 64) atomicAdd(&stats[64 + tid], red[tid] + red[tid + 64] + red[tid + 128] + red[tid + 192]);
}

// ---------------------------------------------------------------------------
__global__ void k_bnfin(const float* __restrict__ stats, const float* __restrict__ g,
                        const float* __restrict__ be, float* __restrict__ coef, float invN) {
    int c = threadIdx.x;
    float m = stats[c] * invN;
    float var = stats[64 + c] * invN - m * m;
    float a = g[c] * rsqrtf(var + EPS);
    coef[c] = a;
    coef[64 + c] = be[c] - m * a;
}

// ---------------------------------------------------------------------------
// Layer-2 gather: agg2[i,c] = mean_j relu(bn1(h1[src_j,c])), bf16 in/out.
// Wave per node (max TLP), neighbor loop unrolled 4-wide -> 4 independent
// 128B L3 reads in flight per wave.
__global__ __launch_bounds__(256) void k_gather2(
    const unsigned short* __restrict__ h1b, const int* __restrict__ rowptr,
    const int* __restrict__ csr, const float* __restrict__ coef1,
    unsigned short* __restrict__ agg2b, int n) {
    int tid = threadIdx.x, c = tid & 63, w = tid >> 6;
    int i = blockIdx.x * 4 + w;
    if (i >= n) return;
    float a1 = coef1[c], b1 = coef1[64 + c];
    int r0 = rowptr[i], r1 = rowptr[i + 1];
    float s = 0.f;
    int j = r0;
    for (; j + 3 < r1; j += 4) {
        int s0 = csr[j], s1 = csr[j + 1], s2 = csr[j + 2], s3 = csr[j + 3];
        float v0 = bf2f(h1b[(size_t)s0 * 64 + c]);
        float v1 = bf2f(h1b[(size_t)s1 * 64 + c]);
        float v2 = bf2f(h1b[(size_t)s2 * 64 + c]);
        float v3 = bf2f(h1b[(size_t)s3 * 64 + c]);
        s += fmaxf(0.f, fmaf(v0, a1, b1)) + fmaxf(0.f, fmaf(v1, a1, b1))
           + fmaxf(0.f, fmaf(v2, a1, b1)) + fmaxf(0.f, fmaf(v3, a1, b1));
    }
    for (; j < r1; ++j) {
        float v0 = bf2f(h1b[(size_t)csr[j] * 64 + c]);
        s += fmaxf(0.f, fmaf(v0, a1, b1));
    }
    float inv = 1.f / fmaxf((float)(r1 - r0), 1.f);
    agg2b[(size_t)i * 64 + c] = f2bf(s * inv);
}

// ---------------------------------------------------------------------------
// Layer-2 dense via MFMA, bf16 operands end-to-end.
// A = [agg2 | relu(bn1(h1))] (K=128), W = [W2l; W2r] staged in LDS as
// per-lane fragments (16 KB). THREE-deep register pipeline (P/Q/R): ~12
// 16B loads in flight per wave while staying in the 4-waves/SIMD VGPR bin.
__global__ __launch_bounds__(256) void k_dense2_mfma(
    const unsigned short* __restrict__ agg2b, const unsigned short* __restrict__ h1b,
    const float* __restrict__ coef1,
    const float* __restrict__ W2l, const float* __restrict__ b2,
    const float* __restrict__ W2r,
    unsigned short* __restrict__ h2b, float* __restrict__ stats, int n) {
    __shared__ unsigned short lds_w[16 * 64 * 8];  // [frag=ks*4+cs][lane][j]
    int tid = threadIdx.x;
    int w = tid >> 6;
    int l = tid & 63;
    int ln = l & 15, kg = l >> 4;

    // Stage W fragments: frag=(k>>5)*4+(c>>4); lane=((k>>3)&3)*16+(c&15); j=k&7
    for (int idx = tid; idx < 4096; idx += 256) {
        int k = idx >> 6, c = idx & 63;
        unsigned short wl = f2bf(W2l[idx]);
        unsigned short wr = f2bf(W2r[idx]);
        int lane = ((k >> 3) & 3) * 16 + (c & 15);
        int slotl = (((k >> 5) * 4 + (c >> 4)) * 64 + lane) * 8 + (k & 7);
        int slotr = ((((k + 64) >> 5) * 4 + (c >> 4)) * 64 + lane) * 8 + (k & 7);
        lds_w[slotl] = wl;
        lds_w[slotr] = wr;
    }
    __syncthreads();

    float bb[4];
#pragma unroll
    for (int cs = 0; cs < 4; ++cs) bb[cs] = b2[cs * 16 + ln];

    // BN1 coefs for this lane's k-slice (k = kg*8+j and 32+kg*8+j)
    float c1a[16], c1b[16];
#pragma unroll
    for (int j = 0; j < 8; ++j) {
        c1a[j]     = coef1[kg * 8 + j];       c1b[j]     = coef1[64 + kg * 8 + j];
        c1a[8 + j] = coef1[32 + kg * 8 + j];  c1b[8 + j] = coef1[96 + kg * 8 + j];
    }

    float ls[4] = {0.f, 0.f, 0.f, 0.f};
    float lq[4] = {0.f, 0.f, 0.f, 0.f};

    const bf16x8* wfrag = (const bf16x8*)lds_w;
    int nt = (n + 15) >> 4;
    int stride = gridDim.x * 4;

#define LOADA(T, A)                                                          \
    {                                                                        \
        int i0_ = (T) << 4;                                                  \
        int row_ = i0_ + ln;                                                 \
        int rr_ = (row_ < n) ? row_ : (n - 1);                               \
        const unsigned short* ar_ = agg2b + (size_t)rr_ * 64 + kg * 8;       \
        const unsigned short* xr_ = h1b + (size_t)rr_ * 64 + kg * 8;         \
        A##0 = *(const bf16x8*)ar_;                                          \
        A##1 = *(const bf16x8*)(ar_ + 32);                                   \
        A##2 = *(const bf16x8*)xr_;                                          \
        A##3 = *(const bf16x8*)(xr_ + 32);                                   \
    }

#define PROCESS(T, A)                                                        \
    {                                                                        \
        bf16x8 u2_, u3_;                                                     \
        _Pragma("unroll")                                                    \
        for (int j = 0; j < 8; ++j) {                                        \
            float f2_ = bf2f((unsigned short)A##2[j]);                       \
            float f3_ = bf2f((unsigned short)A##3[j]);                       \
            u2_[j] = (short)f2bf(fmaxf(0.f, fmaf(f2_, c1a[j], c1b[j])));     \
            u3_[j] = (short)f2bf(fmaxf(0.f, fmaf(f3_, c1a[8 + j], c1b[8 + j]))); \
        }                                                                    \
        f32x4 acc_[4];                                                       \
        _Pragma("unroll")                                                    \
        for (int cs = 0; cs < 4; ++cs) acc_[cs] = (f32x4){0.f, 0.f, 0.f, 0.f}; \
        _Pragma("unroll")                                                    \
        for (int cs = 0; cs < 4; ++cs) {                                     \
            acc_[cs] = __builtin_amdgcn_mfma_f32_16x16x32_bf16(A##0, wfrag[(0 * 4 + cs) * 64 + l], acc_[cs], 0, 0, 0); \
            acc_[cs] = __builtin_amdgcn_mfma_f32_16x16x32_bf16(A##1, wfrag[(1 * 4 + cs) * 64 + l], acc_[cs], 0, 0, 0); \
            acc_[cs] = __builtin_amdgcn_mfma_f32_16x16x32_bf16(u2_,  wfrag[(2 * 4 + cs) * 64 + l], acc_[cs], 0, 0, 0); \
            acc_[cs] = __builtin_amdgcn_mfma_f32_16x16x32_bf16(u3_,  wfrag[(3 * 4 + cs) * 64 + l], acc_[cs], 0, 0, 0); \
        }                                                                    \
        int i0_ = (T) << 4;                                                  \
        _Pragma("unroll")                                                    \
        for (int cs = 0; cs < 4; ++cs) {                                     \
            _Pragma("unroll")                                                \
            for (int r = 0; r < 4; ++r) {                                    \
                int orow_ = i0_ + kg * 4 + r;                                \
                if (orow_ < n) {                                             \
                    float h_ = acc_[cs][r] + bb[cs];                         \
                    unsigned short hb_ = f2bf(h_);                           \
                    h2b[(size_t)orow_ * 64 + cs * 16 + ln] = hb_;            \
                    float hf_ = bf2f(hb_);                                   \
                    ls[cs] += hf_; lq[cs] += hf_ * hf_;                      \
                }                                                            \
            }                                                                \
        }                                                                    \
    }

    bf16x8 P0, P1, P2, P3, Q0, Q1, Q2, Q3, R0, R1, R2, R3;
    int t = blockIdx.x * 4 + w;
    if (t < nt) LOADA(t, P);
    if (t + stride < nt) LOADA(t + stride, Q);
    while (true) {
        if (t >= nt) break;
        { int tp = t + 2 * stride; if (tp < nt) LOADA(tp, R); }
        PROCESS(t, P); t += stride;
        if (t >= nt) break;
        { int tp = t + 2 * stride; if (tp < nt) LOADA(tp, P); }
        PROCESS(t, Q); t += stride;
        if (t >= nt) break;
        { int tp = t + 2 * stride; if (tp < nt) LOADA(tp, Q); }
        PROCESS(t, R); t += stride;
    }
#undef LOADA
#undef PROCESS

#pragma unroll
    for (int cs = 0; cs < 4; ++cs) {
        float s = ls[cs], q = lq[cs];
        s += __shfl_xor(s, 16, 64); s += __shfl_xor(s, 32, 64);
        q += __shfl_xor(q, 16, 64); q += __shfl_xor(q, 32, 64);
        if (kg == 0) {
            atomicAdd(&stats[cs * 16 + ln], s);
            atomicAdd(&stats[64 + cs * 16 + ln], q);
        }
    }
}

// ---------------------------------------------------------------------------
// Finalize: x2 = relu(bn2(h2)) + relu(bn1(h1)); t = x2.W3l; v = x2.W3r.
// 8 nodes per wave -> 16 independent 128B loads in flight.
__global__ __launch_bounds__(256) void k_finalize(
    const unsigned short* __restrict__ h2b, const unsigned short* __restrict__ h1b,
    const float* __restrict__ coef1, const float* __restrict__ coef2,
    const float* __restrict__ W3l, const float* __restrict__ W3r,
    float* __restrict__ tb, float* __restrict__ vb, int n) {
    int tid = threadIdx.x, c = tid & 63, w = tid >> 6;
    int i0 = (blockIdx.x * 4 + w) * 8;
    if (i0 >= n) return;
    float a1 = coef1[c], b1 = coef1[64 + c];
    float a2 = coef2[c], b2 = coef2[64 + c];
    float wl = W3l[c], wr = W3r[c];
    float tv[8], vv[8];
#pragma unroll
    for (int q = 0; q < 8; ++q) {
        int i = i0 + q; int ic = (i < n) ? i : (n - 1);
        float h1v = bf2f(h1b[(size_t)ic * 64 + c]);
        float h2v = bf2f(h2b[(size_t)ic * 64 + c]);
        float x1v = fmaxf(0.f, fmaf(h1v, a1, b1));
        float x2v = fmaxf(0.f, fmaf(h2v, a2, b2)) + x1v;
        tv[q] = x2v * wl; vv[q] = x2v * wr;
    }
#pragma unroll
    for (int q = 0; q < 8; ++q) {
        float t = tv[q], v = vv[q];
#pragma unroll
        for (int o = 32; o > 0; o >>= 1) {
            t += __shfl_xor(t, o, 64);
            v += __shfl_xor(v, o, 64);
        }
        if (c == 0 && i0 + q < n) { tb[i0 + q] = t; vb[i0 + q] = v; }
    }
}

// ---------------------------------------------------------------------------
// Layer-3 gather + output, neighbor loop unrolled 4-wide.
__global__ void k_gather3(const float* __restrict__ tb, const float* __restrict__ vb,
                          const int* __restrict__ rowptr, const int* __restrict__ csr,
                          const float* __restrict__ b3, float* __restrict__ out, int n) {
    int i = blockIdx.x * blockDim.x + threadIdx.x;
    if (i >= n) return;
    int r0 = rowptr[i], r1 = rowptr[i + 1];
    float s = 0.f;
    int j = r0;
    for (; j + 3 < r1; j += 4)
        s += tb[csr[j]] + tb[csr[j + 1]] + tb[csr[j + 2]] + tb[csr[j + 3]];
    for (; j < r1; ++j) s += tb[csr[j]];
    float inv = 1.f / fmaxf((float)(r1 - r0), 1.f);
    out[i] = fmaf(s, inv, b3[0] + vb[i]);
}

// ---------------------------------------------------------------------------
// Workspace (4B units, N=500k, E=1.25M; cap 256 MiB = 67,108,864 units):
//   h1b 32N + agg2b 32N + h2b 32N + R 2N + rowptr N+1 + csr E + small
//   = ~50.8M units = 203 MB (safe)
extern "C" void kernel_launch(void* const* d_in, const int* in_sizes, int n_in,
                              void* d_out, int out_size, void* d_ws, size_t ws_size,
                              hipStream_t stream) {
    const float* x   = (const float*)d_in[0];
    const int*   ei  = (const int*)d_in[1];
    const float* W1l = (const float*)d_in[2];
    const float* b1  = (const float*)d_in[3];
    const float* W1r = (const float*)d_in[4];
    const float* g1  = (const float*)d_in[5];
    const float* be1 = (const float*)d_in[6];
    const float* W2l = (const float*)d_in[7];
    const float* b2  = (const float*)d_in[8];
    const float* W2r = (const float*)d_in[9];
    const float* g2  = (const float*)d_in[10];
    const float* be2 = (const float*)d_in[11];
    const float* W3l = (const float*)d_in[12];
    const float* b3  = (const float*)d_in[13];
    const float* W3r = (const float*)d_in[14];

    int N = in_sizes[0] / 2;
    int E = in_sizes[1] / 2;

    float* ws   = (float*)d_ws;
    size_t nn   = (size_t)N;
    unsigned short* h1b   = (unsigned short*)ws;             // 32N units
    unsigned short* agg2b = (unsigned short*)(ws + 32 * nn); // 32N units
    unsigned short* h2b   = (unsigned short*)(ws + 64 * nn); // 32N units
    float* R     = ws + 96 * nn;           // 2N time-shared region
    int*   cursor = (int*)R;               //   phase 1: CSR build (N+1 ints)
    float* agg1   = R;                     //   phase 2: layer-1 agg (2N f32)
    float* tb     = R;                     //   phase 3: layer-3 t (N f32)
    float* vb     = R + nn;                //   phase 3: layer-3 v (N f32)
    int*   rowptr = (int*)(ws + 98 * nn);  // N+1 (doubles as histogram cnt)
    int*   csr    = rowptr + (N + 1);      // E
    int*   bsums  = csr + E;               // 2048
    float* stats  = (float*)(bsums + 2048);// 256: s1,q1 | s2,q2
    float* coef   = stats + 256;           // 256: a1,b1 | a2,b2
    int*   flag   = (int*)(coef + 256);    // 64 (padded)

    hipMemsetAsync(rowptr, 0, (size_t)(N + 1) * sizeof(int), stream);
    hipMemsetAsync(stats, 0, 256 * sizeof(float), stream);

    k_detect<<<1, 1, 0, stream>>>(ei, flag);

    int ge = (E + 255) / 256;
    int nb = (N + 1023) / 1024;
    k_hist<<<ge, 256, 0, stream>>>(ei, flag, E, rowptr);
    k_scanA<<<nb, 256, 0, stream>>>(rowptr, N, bsums);
    k_scanB<<<1, 256, 0, stream>>>(bsums, nb, rowptr, N);
    k_scanC<<<nb, 256, 0, stream>>>(rowptr, N, bsums, cursor);
    k_fill<<<ge, 256, 0, stream>>>(ei, flag, E, cursor, csr);
    // cursor dead; R becomes agg1

    k_gather1<<<(N + 255) / 256, 256, 0, stream>>>(x, rowptr, csr, agg1, N);
    k_dense1<<<1024, 256, 0, stream>>>(x, agg1, W1l, b1, W1r, h1b, stats, N);
    k_bnfin<<<1, 64, 0, stream>>>(stats, g1, be1, coef, 1.0f / (float)N);
    // agg1 dead after dense1

    int gw = (N + 3) / 4;  // wave-per-node kernels
    k_gather2<<<gw, 256, 0, stream>>>(h1b, rowptr, csr, coef, agg2b, N);
    k_dense2_mfma<<<1024, 256, 0, stream>>>(agg2b, h1b, coef, W2l, b2, W2r, h2b, stats + 128, N);
    k_bnfin<<<1, 64, 0, stream>>>(stats + 128, g2, be2, coef + 128, 1.0f / (float)N);

    // R becomes tb/vb
    k_finalize<<<(N + 31) / 32, 256, 0, stream>>>(h2b, h1b, coef, coef + 128,
                                                  W3l, W3r, tb, vb, N);
    k_gather3<<<(N + 255) / 256, 256, 0, stream>>>(tb, vb, rowptr, csr, b3, (float*)d_out, N);
}

// Round 8
// 549.793 us; speedup vs baseline: 1.4989x; 1.2605x over previous
//
#include <hip/hip_runtime.h>

#define EPS 1e-5f

typedef __attribute__((ext_vector_type(8))) short bf16x8;
typedef __attribute__((ext_vector_type(4))) float f32x4;

__device__ __forceinline__ unsigned short f2bf(float f) {
    unsigned u = __float_as_uint(f);
    u += 0x7fffu + ((u >> 16) & 1u);
    return (unsigned short)(u >> 16);
}
__device__ __forceinline__ float bf2f(unsigned short s) {
    return __uint_as_float(((unsigned)s) << 16);
}

// ---------------------------------------------------------------------------
// Edge-index dtype detection: JAX may emit int32 (x64 disabled) or int64.
__global__ void k_detect(const int* __restrict__ ei, int* __restrict__ flag) {
    if (blockIdx.x == 0 && threadIdx.x == 0) {
        int is64 = 1;
        for (int k = 0; k < 16; ++k) is64 &= (ei[2 * k + 1] == 0) ? 1 : 0;
        *flag = is64;
    }
}

// ---------------------------------------------------------------------------
// CSR build: histogram -> exclusive scan (3 kernels) -> fill
__global__ void k_hist(const int* __restrict__ ei, const int* __restrict__ flag,
                       int E, int* __restrict__ cnt) {
    int e = blockIdx.x * blockDim.x + threadIdx.x;
    if (e >= E) return;
    int d = (*flag) ? (int)((const long long*)ei)[E + e] : ei[E + e];
    atomicAdd(&cnt[d], 1);
}

__device__ __forceinline__ int block_incl_scan(int v, int tid, int* total) {
    __shared__ int wsum[4];
    __shared__ int tot;
#pragma unroll
    for (int o = 1; o < 64; o <<= 1) {
        int u = __shfl_up(v, o, 64);
        if ((tid & 63) >= o) v += u;
    }
    if ((tid & 63) == 63) wsum[tid >> 6] = v;
    __syncthreads();
    int w = tid >> 6, add = 0;
    if (w > 0) add += wsum[0];
    if (w > 1) add += wsum[1];
    if (w > 2) add += wsum[2];
    v += add;
    if (tid == 255) tot = v;
    __syncthreads();
    *total = tot;
    __syncthreads();
    return v;
}

__global__ __launch_bounds__(256) void k_scanA(const int* __restrict__ cnt, int n,
                                               int* __restrict__ bsums) {
    int tid = threadIdx.x;
    int idx = blockIdx.x * 1024 + tid * 4;
    int s = 0;
#pragma unroll
    for (int k = 0; k < 4; ++k) { int i = idx + k; if (i < n) s += cnt[i]; }
#pragma unroll
    for (int o = 32; o > 0; o >>= 1) s += __shfl_xor(s, o, 64);
    __shared__ int ws[4];
    if ((tid & 63) == 0) ws[tid >> 6] = s;
    __syncthreads();
    if (tid == 0) bsums[blockIdx.x] = ws[0] + ws[1] + ws[2] + ws[3];
}

__global__ __launch_bounds__(256) void k_scanB(int* __restrict__ bsums, int nb,
                                               int* __restrict__ rowptr, int N) {
    int tid = threadIdx.x;
    __shared__ int sh_carry;
    if (tid == 0) sh_carry = 0;
    __syncthreads();
    int niter = (nb + 255) / 256;
    for (int it = 0; it < niter; ++it) {
        int i = it * 256 + tid;
        int v = (i < nb) ? bsums[i] : 0;
        int tot;
        int inc = block_incl_scan(v, tid, &tot);
        int carry = sh_carry;
        if (i < nb) bsums[i] = carry + inc - v;
        __syncthreads();
        if (tid == 0) sh_carry = carry + tot;
        __syncthreads();
    }
    if (tid == 0) rowptr[N] = sh_carry;
}

__global__ __launch_bounds__(256) void k_scanC(int* __restrict__ cnt_rowptr, int n,
                                               const int* __restrict__ bsums,
                                               int* __restrict__ cursor) {
    int tid = threadIdx.x;
    int idx = blockIdx.x * 1024 + tid * 4;
    int v[4]; int s = 0;
#pragma unroll
    for (int k = 0; k < 4; ++k) { int i = idx + k; v[k] = (i < n) ? cnt_rowptr[i] : 0; s += v[k]; }
    int tot;
    int inc = block_incl_scan(s, tid, &tot);
    int off = bsums[blockIdx.x] + inc - s;
#pragma unroll
    for (int k = 0; k < 4; ++k) {
        int i = idx + k;
        if (i < n) { cnt_rowptr[i] = off; cursor[i] = off; off += v[k]; }
    }
}

__global__ void k_fill(const int* __restrict__ ei, const int* __restrict__ flag, int E,
                       int* __restrict__ cursor, int* __restrict__ csr) {
    int e = blockIdx.x * blockDim.x + threadIdx.x;
    if (e >= E) return;
    int s, d;
    if (*flag) {
        s = (int)((const long long*)ei)[e];
        d = (int)((const long long*)ei)[E + e];
    } else {
        s = ei[e]; d = ei[E + e];
    }
    int pos = atomicAdd(&cursor[d], 1);
    csr[pos] = s;
}

// ---------------------------------------------------------------------------
__global__ void k_gather1(const float* __restrict__ x, const int* __restrict__ rowptr,
                          const int* __restrict__ csr, float* __restrict__ agg1, int n) {
    int i = blockIdx.x * blockDim.x + threadIdx.x;
    if (i >= n) return;
    int r0 = rowptr[i], r1 = rowptr[i + 1];
    float s0 = 0.f, s1 = 0.f;
    for (int j = r0; j < r1; ++j) {
        float2 v = ((const float2*)x)[csr[j]];
        s0 += v.x; s1 += v.y;
    }
    float inv = 1.f / fmaxf((float)(r1 - r0), 1.f);
    agg1[2 * i] = s0 * inv;
    agg1[2 * i + 1] = s1 * inv;
}

// ---------------------------------------------------------------------------
// Layer-1 dense (K=2): h1 = agg1@W1l + b1 + x@W1r -> bf16 store.
// BN stats accumulated on the TRUNCATED value (self-consistent with readers).
__global__ __launch_bounds__(256) void k_dense1(
    const float* __restrict__ x, const float* __restrict__ agg1,
    const float* __restrict__ W1l, const float* __restrict__ b1,
    const float* __restrict__ W1r,
    unsigned short* __restrict__ h1b, float* __restrict__ stats, int n) {
    int tid = threadIdx.x, c = tid & 63, w = tid >> 6;
    float wl0 = W1l[c], wl1 = W1l[64 + c];
    float wr0 = W1r[c], wr1 = W1r[64 + c];
    float bb = b1[c];
    float ls = 0.f, lq = 0.f;
    for (int i = blockIdx.x * 4 + w; i < n; i += gridDim.x * 4) {
        float a0 = agg1[2 * i], a1 = agg1[2 * i + 1];
        float x0 = x[2 * i], x1v = x[2 * i + 1];
        float h = fmaf(a0, wl0, fmaf(a1, wl1, fmaf(x0, wr0, fmaf(x1v, wr1, bb))));
        unsigned short hb = f2bf(h);
        h1b[(size_t)i * 64 + c] = hb;
        float hf = bf2f(hb);
        ls += hf; lq += hf * hf;
    }
    __shared__ float red[256];
    red[tid] = ls; __syncthreads();
    if (tid < 64) atomicAdd(&stats[tid], red[tid] + red[tid + 64] + red[tid + 128] + red[tid + 192]);
    __syncthreads();
    red[tid] = lq; __syncthreads();
    if (tid < 64) atomicAdd(&stats[64 + tid], red[tid] + red[tid + 64] + red[tid + 128] + red[tid + 192]);
}

// ---------------------------------------------------------------------------
__global__ void k_bnfin(const float* __restrict__ stats, const float* __restrict__ g,
                        const float* __restrict__ be, float* __restrict__ coef, float invN) {
    int c = threadIdx.x;
    float m = stats[c] * invN;
    float var = stats[64 + c] * invN - m * m;
    float a = g[c] * rsqrtf(var + EPS);
    coef[c] = a;
    coef[64 + c] = be[c] - m * a;
}

// ---------------------------------------------------------------------------
// Pre-transform (linear commute): per node i,
//   x1 = relu(bn1(h1_i));  y_i = x1@W2l;  z_i = x1@W2r + b2.
// Pure streaming MFMA: no gathered inputs. Output staged in wave-private LDS
// and stored as 2KB fully-coalesced lines (fixes the partial-line store wall).
#define LROW 72  // LDS row stride in shorts

__global__ __launch_bounds__(256) void k_dense_pre(
    const unsigned short* __restrict__ h1b, const float* __restrict__ coef1,
    const float* __restrict__ W2l, const float* __restrict__ b2,
    const float* __restrict__ W2r,
    unsigned short* __restrict__ y, unsigned short* __restrict__ z, int n) {
    __shared__ unsigned short lds_w[16 * 64 * 8];                 // 16 KB
    __shared__ __align__(16) unsigned short lds_y[4][16 * LROW];  // per-wave y tile
    __shared__ __align__(16) unsigned short lds_z[4][16 * LROW];  // per-wave z tile
    int tid = threadIdx.x, w = tid >> 6, l = tid & 63, ln = l & 15, kg = l >> 4;

    // Stage W2l frags in slots 0..7, W2r in slots 8..15.
    // K=64: frag = (k>>5)*4 + (c>>4); lane = ((k>>3)&3)*16 + (c&15); j = k&7.
    for (int idx = tid; idx < 4096; idx += 256) {
        int k = idx >> 6, c = idx & 63;
        int lane = ((k >> 3) & 3) * 16 + (c & 15);
        int fbase = ((k >> 5) * 4 + (c >> 4)) * 64 + lane;
        lds_w[fbase * 8 + (k & 7)] = f2bf(W2l[idx]);
        lds_w[(8 * 64 + fbase) * 8 + (k & 7)] = f2bf(W2r[idx]);
    }
    __syncthreads();

    float bb[4];
#pragma unroll
    for (int cs = 0; cs < 4; ++cs) bb[cs] = b2[cs * 16 + ln];
    float c1a[16], c1b[16];
#pragma unroll
    for (int j = 0; j < 8; ++j) {
        c1a[j]     = coef1[kg * 8 + j];       c1b[j]     = coef1[64 + kg * 8 + j];
        c1a[8 + j] = coef1[32 + kg * 8 + j];  c1b[8 + j] = coef1[96 + kg * 8 + j];
    }

    unsigned short* Ys = lds_y[w];
    unsigned short* Zs = lds_z[w];
    const bf16x8* wfrag = (const bf16x8*)lds_w;
    int nt = (n + 15) >> 4;
    int stride = gridDim.x * 4;

#define LOADH(T, A)                                                          \
    {                                                                        \
        int row_ = ((T) << 4) + ln;                                          \
        int rr_ = (row_ < n) ? row_ : (n - 1);                               \
        const unsigned short* xr_ = h1b + (size_t)rr_ * 64 + kg * 8;         \
        A##0 = *(const bf16x8*)xr_;                                          \
        A##1 = *(const bf16x8*)(xr_ + 32);                                   \
    }

#define PROCESSH(T, A)                                                       \
    {                                                                        \
        bf16x8 u0_, u1_;                                                     \
        _Pragma("unroll")                                                    \
        for (int j = 0; j < 8; ++j) {                                        \
            float f0_ = bf2f((unsigned short)A##0[j]);                       \
            float f1_ = bf2f((unsigned short)A##1[j]);                       \
            u0_[j] = (short)f2bf(fmaxf(0.f, fmaf(f0_, c1a[j], c1b[j])));     \
            u1_[j] = (short)f2bf(fmaxf(0.f, fmaf(f1_, c1a[8 + j], c1b[8 + j]))); \
        }                                                                    \
        f32x4 ya_[4], za_[4];                                                \
        _Pragma("unroll")                                                    \
        for (int cs = 0; cs < 4; ++cs) {                                     \
            ya_[cs] = (f32x4){0.f, 0.f, 0.f, 0.f};                           \
            za_[cs] = (f32x4){0.f, 0.f, 0.f, 0.f};                           \
        }                                                                    \
        _Pragma("unroll")                                                    \
        for (int cs = 0; cs < 4; ++cs) {                                     \
            ya_[cs] = __builtin_amdgcn_mfma_f32_16x16x32_bf16(u0_, wfrag[(0 * 4 + cs) * 64 + l], ya_[cs], 0, 0, 0);  \
            ya_[cs] = __builtin_amdgcn_mfma_f32_16x16x32_bf16(u1_, wfrag[(1 * 4 + cs) * 64 + l], ya_[cs], 0, 0, 0);  \
            za_[cs] = __builtin_amdgcn_mfma_f32_16x16x32_bf16(u0_, wfrag[(8 + cs) * 64 + l], za_[cs], 0, 0, 0);      \
            za_[cs] = __builtin_amdgcn_mfma_f32_16x16x32_bf16(u1_, wfrag[(12 + cs) * 64 + l], za_[cs], 0, 0, 0);     \
        }                                                                    \
        _Pragma("unroll")                                                    \
        for (int cs = 0; cs < 4; ++cs) {                                     \
            _Pragma("unroll")                                                \
            for (int r = 0; r < 4; ++r) {                                    \
                Ys[(kg * 4 + r) * LROW + cs * 16 + ln] = f2bf(ya_[cs][r]);   \
                Zs[(kg * 4 + r) * LROW + cs * 16 + ln] = f2bf(za_[cs][r] + bb[cs]); \
            }                                                                \
        }                                                                    \
        asm volatile("s_waitcnt lgkmcnt(0)" ::: "memory");                   \
        int base_ = (T) << 4;                                                \
        int orow_ = l >> 2, oc_ = (l & 3) * 16;                              \
        if (base_ + orow_ < n) {                                             \
            const bf16x8* yp_ = (const bf16x8*)(Ys + orow_ * LROW + oc_);    \
            const bf16x8* zp_ = (const bf16x8*)(Zs + orow_ * LROW + oc_);    \
            bf16x8* yd_ = (bf16x8*)(y + (size_t)(base_ + orow_) * 64 + oc_); \
            bf16x8* zd_ = (bf16x8*)(z + (size_t)(base_ + orow_) * 64 + oc_); \
            yd_[0] = yp_[0]; yd_[1] = yp_[1];                                \
            zd_[0] = zp_[0]; zd_[1] = zp_[1];                                \
        }                                                                    \
        asm volatile("s_waitcnt lgkmcnt(0)" ::: "memory");                   \
    }

    bf16x8 P0, P1, Q0, Q1;
    int t = blockIdx.x * 4 + w;
    if (t < nt) {
        LOADH(t, P);
        while (t < nt) {
            int t1 = t + stride;
            if (t1 < nt) LOADH(t1, Q);
            PROCESSH(t, P);
            int t2 = t1 + stride;
            if (t2 < nt) LOADH(t2, P);
            if (t1 < nt) PROCESSH(t1, Q);
            t = t2;
        }
    }
#undef LOADH
#undef PROCESSH
}

// ---------------------------------------------------------------------------
// Gather + combine: h2_i = mean_j y[src_j] + z_i   (z already holds +b2).
// Written IN PLACE over z. BN2 stats fused (block-reduced, one atomic/chan).
// Wave per node, grid-stride; neighbor loop unrolled 4-wide.
__global__ __launch_bounds__(256) void k_gather2b(
    const unsigned short* __restrict__ y, const int* __restrict__ rowptr,
    const int* __restrict__ csr, unsigned short* zh2,
    float* __restrict__ stats, int n) {
    int tid = threadIdx.x, c = tid & 63, w = tid >> 6;
    float ls = 0.f, lq = 0.f;
    for (int i = blockIdx.x * 4 + w; i < n; i += gridDim.x * 4) {
        int r0 = rowptr[i], r1 = rowptr[i + 1];
        float s = 0.f;
        int j = r0;
        for (; j + 3 < r1; j += 4) {
            int s0 = csr[j], s1 = csr[j + 1], s2 = csr[j + 2], s3 = csr[j + 3];
            s += bf2f(y[(size_t)s0 * 64 + c]) + bf2f(y[(size_t)s1 * 64 + c])
               + bf2f(y[(size_t)s2 * 64 + c]) + bf2f(y[(size_t)s3 * 64 + c]);
        }
        for (; j < r1; ++j) s += bf2f(y[(size_t)csr[j] * 64 + c]);
        float inv = 1.f / fmaxf((float)(r1 - r0), 1.f);
        float h = fmaf(s, inv, bf2f(zh2[(size_t)i * 64 + c]));
        unsigned short hb = f2bf(h);
        zh2[(size_t)i * 64 + c] = hb;
        float hf = bf2f(hb);
        ls += hf; lq += hf * hf;
    }
    __shared__ float red[256];
    red[tid] = ls; __syncthreads();
    if (tid < 64) atomicAdd(&stats[tid], red[tid] + red[tid + 64] + red[tid + 128] + red[tid + 192]);
    __syncthreads();
    red[tid] = lq; __syncthreads();
    if (tid < 64) atomicAdd(&stats[64 + tid], red[tid] + red[tid + 64] + red[tid + 128] + red[tid + 192]);
}

// ---------------------------------------------------------------------------
// Finalize: x2 = relu(bn2(h2)) + relu(bn1(h1)); t = x2.W3l; v = x2.W3r.
__global__ __launch_bounds__(256) void k_finalize(
    const unsigned short* __restrict__ h2b, const unsigned short* __restrict__ h1b,
    const float* __restrict__ coef1, const float* __restrict__ coef2,
    const float* __restrict__ W3l, const float* __restrict__ W3r,
    float* __restrict__ tb, float* __restrict__ vb, int n) {
    int tid = threadIdx.x, c = tid & 63, w = tid >> 6;
    int i0 = (blockIdx.x * 4 + w) * 8;
    if (i0 >= n) return;
    float a1 = coef1[c], b1 = coef1[64 + c];
    float a2 = coef2[c], b2 = coef2[64 + c];
    float wl = W3l[c], wr = W3r[c];
    float tv[8], vv[8];
#pragma unroll
    for (int q = 0; q < 8; ++q) {
        int i = i0 + q; int ic = (i < n) ? i : (n - 1);
        float h1v = bf2f(h1b[(size_t)ic * 64 + c]);
        float h2v = bf2f(h2b[(size_t)ic * 64 + c]);
        float x1v = fmaxf(0.f, fmaf(h1v, a1, b1));
        float x2v = fmaxf(0.f, fmaf(h2v, a2, b2)) + x1v;
        tv[q] = x2v * wl; vv[q] = x2v * wr;
    }
#pragma unroll
    for (int q = 0; q < 8; ++q) {
        float t = tv[q], v = vv[q];
#pragma unroll
        for (int o = 32; o > 0; o >>= 1) {
            t += __shfl_xor(t, o, 64);
            v += __shfl_xor(v, o, 64);
        }
        if (c == 0 && i0 + q < n) { tb[i0 + q] = t; vb[i0 + q] = v; }
    }
}

// ---------------------------------------------------------------------------
__global__ void k_gather3(const float* __restrict__ tb, const float* __restrict__ vb,
                          const int* __restrict__ rowptr, const int* __restrict__ csr,
                          const float* __restrict__ b3, float* __restrict__ out, int n) {
    int i = blockIdx.x * blockDim.x + threadIdx.x;
    if (i >= n) return;
    int r0 = rowptr[i], r1 = rowptr[i + 1];
    float s = 0.f;
    int j = r0;
    for (; j + 3 < r1; j += 4)
        s += tb[csr[j]] + tb[csr[j + 1]] + tb[csr[j + 2]] + tb[csr[j + 3]];
    for (; j < r1; ++j) s += tb[csr[j]];
    float inv = 1.f / fmaxf((float)(r1 - r0), 1.f);
    out[i] = fmaf(s, inv, b3[0] + vb[i]);
}

// ---------------------------------------------------------------------------
// Workspace (4B units, N=500k, E=1.25M; cap 256 MiB = 67,108,864 units):
//   h1b 32N + y 32N + zh2 32N + R 2N + rowptr N+1 + csr E + small
//   = ~50.8M units = 203 MB (safe)
extern "C" void kernel_launch(void* const* d_in, const int* in_sizes, int n_in,
                              void* d_out, int out_size, void* d_ws, size_t ws_size,
                              hipStream_t stream) {
    const float* x   = (const float*)d_in[0];
    const int*   ei  = (const int*)d_in[1];
    const float* W1l = (const float*)d_in[2];
    const float* b1  = (const float*)d_in[3];
    const float* W1r = (const float*)d_in[4];
    const float* g1  = (const float*)d_in[5];
    const float* be1 = (const float*)d_in[6];
    const float* W2l = (const float*)d_in[7];
    const float* b2  = (const float*)d_in[8];
    const float* W2r = (const float*)d_in[9];
    const float* g2  = (const float*)d_in[10];
    const float* be2 = (const float*)d_in[11];
    const float* W3l = (const float*)d_in[12];
    const float* b3  = (const float*)d_in[13];
    const float* W3r = (const float*)d_in[14];

    int N = in_sizes[0] / 2;
    int E = in_sizes[1] / 2;

    float* ws   = (float*)d_ws;
    size_t nn   = (size_t)N;
    unsigned short* h1b = (unsigned short*)ws;             // 32N units
    unsigned short* y   = (unsigned short*)(ws + 32 * nn); // 32N units
    unsigned short* zh2 = (unsigned short*)(ws + 64 * nn); // 32N units (z -> h2)
    float* R     = ws + 96 * nn;           // 2N time-shared region
    int*   cursor = (int*)R;               //   phase 1: CSR build (N+1 ints)
    float* agg1   = R;                     //   phase 2: layer-1 agg (2N f32)
    float* tb     = R;                     //   phase 3: layer-3 t (N f32)
    float* vb     = R + nn;                //   phase 3: layer-3 v (N f32)
    int*   rowptr = (int*)(ws + 98 * nn);  // N+1 (doubles as histogram cnt)
    int*   csr    = rowptr + (N + 1);      // E
    int*   bsums  = csr + E;               // 2048
    float* stats  = (float*)(bsums + 2048);// 256: s1,q1 | s2,q2
    float* coef   = stats + 256;           // 256: a1,b1 | a2,b2
    int*   flag   = (int*)(coef + 256);    // 64 (padded)

    hipMemsetAsync(rowptr, 0, (size_t)(N + 1) * sizeof(int), stream);
    hipMemsetAsync(stats, 0, 256 * sizeof(float), stream);

    k_detect<<<1, 1, 0, stream>>>(ei, flag);

    int ge = (E + 255) / 256;
    int nb = (N + 1023) / 1024;
    k_hist<<<ge, 256, 0, stream>>>(ei, flag, E, rowptr);
    k_scanA<<<nb, 256, 0, stream>>>(rowptr, N, bsums);
    k_scanB<<<1, 256, 0, stream>>>(bsums, nb, rowptr, N);
    k_scanC<<<nb, 256, 0, stream>>>(rowptr, N, bsums, cursor);
    k_fill<<<ge, 256, 0, stream>>>(ei, flag, E, cursor, csr);
    // cursor dead; R becomes agg1

    k_gather1<<<(N + 255) / 256, 256, 0, stream>>>(x, rowptr, csr, agg1, N);
    k_dense1<<<1024, 256, 0, stream>>>(x, agg1, W1l, b1, W1r, h1b, stats, N);
    k_bnfin<<<1, 64, 0, stream>>>(stats, g1, be1, coef, 1.0f / (float)N);
    // agg1 dead after dense1

    k_dense_pre<<<2048, 256, 0, stream>>>(h1b, coef, W2l, b2, W2r, y, zh2, N);
    k_gather2b<<<2048, 256, 0, stream>>>(y, rowptr, csr, zh2, stats + 128, N);
    k_bnfin<<<1, 64, 0, stream>>>(stats + 128, g2, be2, coef + 128, 1.0f / (float)N);

    // R becomes tb/vb
    k_finalize<<<(N + 31) / 32, 256, 0, stream>>>(zh2, h1b, coef, coef + 128,
                                                  W3l, W3r, tb, vb, N);
    k_gather3<<<(N + 255) / 256, 256, 0, stream>>>(tb, vb, rowptr, csr, b3, (float*)d_out, N);
}

// Round 9
// 495.055 us; speedup vs baseline: 1.6646x; 1.1106x over previous
//
#include <hip/hip_runtime.h>

#define EPS 1e-5f

typedef __attribute__((ext_vector_type(8))) short bf16x8;
typedef __attribute__((ext_vector_type(4))) float f32x4;

__device__ __forceinline__ unsigned short f2bf(float f) {
    unsigned u = __float_as_uint(f);
    u += 0x7fffu + ((u >> 16) & 1u);
    return (unsigned short)(u >> 16);
}
__device__ __forceinline__ float bf2f(unsigned short s) {
    return __uint_as_float(((unsigned)s) << 16);
}

// ---------------------------------------------------------------------------
// Edge-index dtype detection: JAX may emit int32 (x64 disabled) or int64.
__global__ void k_detect(const int* __restrict__ ei, int* __restrict__ flag) {
    if (blockIdx.x == 0 && threadIdx.x == 0) {
        int is64 = 1;
        for (int k = 0; k < 16; ++k) is64 &= (ei[2 * k + 1] == 0) ? 1 : 0;
        *flag = is64;
    }
}

// ---------------------------------------------------------------------------
// CSR build: histogram -> exclusive scan (3 kernels) -> fill
__global__ void k_hist(const int* __restrict__ ei, const int* __restrict__ flag,
                       int E, int* __restrict__ cnt) {
    int e = blockIdx.x * blockDim.x + threadIdx.x;
    if (e >= E) return;
    int d = (*flag) ? (int)((const long long*)ei)[E + e] : ei[E + e];
    atomicAdd(&cnt[d], 1);
}

__device__ __forceinline__ int block_incl_scan(int v, int tid, int* total) {
    __shared__ int wsum[4];
    __shared__ int tot;
#pragma unroll
    for (int o = 1; o < 64; o <<= 1) {
        int u = __shfl_up(v, o, 64);
        if ((tid & 63) >= o) v += u;
    }
    if ((tid & 63) == 63) wsum[tid >> 6] = v;
    __syncthreads();
    int w = tid >> 6, add = 0;
    if (w > 0) add += wsum[0];
    if (w > 1) add += wsum[1];
    if (w > 2) add += wsum[2];
    v += add;
    if (tid == 255) tot = v;
    __syncthreads();
    *total = tot;
    __syncthreads();
    return v;
}

__global__ __launch_bounds__(256) void k_scanA(const int* __restrict__ cnt, int n,
                                               int* __restrict__ bsums) {
    int tid = threadIdx.x;
    int idx = blockIdx.x * 1024 + tid * 4;
    int s = 0;
#pragma unroll
    for (int k = 0; k < 4; ++k) { int i = idx + k; if (i < n) s += cnt[i]; }
#pragma unroll
    for (int o = 32; o > 0; o >>= 1) s += __shfl_xor(s, o, 64);
    __shared__ int ws[4];
    if ((tid & 63) == 0) ws[tid >> 6] = s;
    __syncthreads();
    if (tid == 0) bsums[blockIdx.x] = ws[0] + ws[1] + ws[2] + ws[3];
}

__global__ __launch_bounds__(256) void k_scanB(int* __restrict__ bsums, int nb,
                                               int* __restrict__ rowptr, int N) {
    int tid = threadIdx.x;
    __shared__ int sh_carry;
    if (tid == 0) sh_carry = 0;
    __syncthreads();
    int niter = (nb + 255) / 256;
    for (int it = 0; it < niter; ++it) {
        int i = it * 256 + tid;
        int v = (i < nb) ? bsums[i] : 0;
        int tot;
        int inc = block_incl_scan(v, tid, &tot);
        int carry = sh_carry;
        if (i < nb) bsums[i] = carry + inc - v;
        __syncthreads();
        if (tid == 0) sh_carry = carry + tot;
        __syncthreads();
    }
    if (tid == 0) rowptr[N] = sh_carry;
}

__global__ __launch_bounds__(256) void k_scanC(int* __restrict__ cnt_rowptr, int n,
                                               const int* __restrict__ bsums,
                                               int* __restrict__ cursor) {
    int tid = threadIdx.x;
    int idx = blockIdx.x * 1024 + tid * 4;
    int v[4]; int s = 0;
#pragma unroll
    for (int k = 0; k < 4; ++k) { int i = idx + k; v[k] = (i < n) ? cnt_rowptr[i] : 0; s += v[k]; }
    int tot;
    int inc = block_incl_scan(s, tid, &tot);
    int off = bsums[blockIdx.x] + inc - s;
#pragma unroll
    for (int k = 0; k < 4; ++k) {
        int i = idx + k;
        if (i < n) { cnt_rowptr[i] = off; cursor[i] = off; off += v[k]; }
    }
}

__global__ void k_fill(const int* __restrict__ ei, const int* __restrict__ flag, int E,
                       int* __restrict__ cursor, int* __restrict__ csr) {
    int e = blockIdx.x * blockDim.x + threadIdx.x;
    if (e >= E) return;
    int s, d;
    if (*flag) {
        s = (int)((const long long*)ei)[e];
        d = (int)((const long long*)ei)[E + e];
    } else {
        s = ei[e]; d = ei[E + e];
    }
    int pos = atomicAdd(&cursor[d], 1);
    csr[pos] = s;
}

// ---------------------------------------------------------------------------
__global__ void k_gather1(const float* __restrict__ x, const int* __restrict__ rowptr,
                          const int* __restrict__ csr, float* __restrict__ agg1, int n) {
    int i = blockIdx.x * blockDim.x + threadIdx.x;
    if (i >= n) return;
    int r0 = rowptr[i], r1 = rowptr[i + 1];
    float s0 = 0.f, s1 = 0.f;
    for (int j = r0; j < r1; ++j) {
        float2 v = ((const float2*)x)[csr[j]];
        s0 += v.x; s1 += v.y;
    }
    float inv = 1.f / fmaxf((float)(r1 - r0), 1.f);
    agg1[2 * i] = s0 * inv;
    agg1[2 * i + 1] = s1 * inv;
}

// ---------------------------------------------------------------------------
// Layer-1 dense (K=2): h1 = agg1@W1l + b1 + x@W1r -> bf16 store.
// BN stats accumulated on the TRUNCATED value (self-consistent with readers).
__global__ __launch_bounds__(256) void k_dense1(
    const float* __restrict__ x, const float* __restrict__ agg1,
    const float* __restrict__ W1l, const float* __restrict__ b1,
    const float* __restrict__ W1r,
    unsigned short* __restrict__ h1b, float* __restrict__ stats, int n) {
    int tid = threadIdx.x, c = tid & 63, w = tid >> 6;
    float wl0 = W1l[c], wl1 = W1l[64 + c];
    float wr0 = W1r[c], wr1 = W1r[64 + c];
    float bb = b1[c];
    float ls = 0.f, lq = 0.f;
    for (int i = blockIdx.x * 4 + w; i < n; i += gridDim.x * 4) {
        float a0 = agg1[2 * i], a1 = agg1[2 * i + 1];
        float x0 = x[2 * i], x1v = x[2 * i + 1];
        float h = fmaf(a0, wl0, fmaf(a1, wl1, fmaf(x0, wr0, fmaf(x1v, wr1, bb))));
        unsigned short hb = f2bf(h);
        h1b[(size_t)i * 64 + c] = hb;
        float hf = bf2f(hb);
        ls += hf; lq += hf * hf;
    }
    __shared__ float red[256];
    red[tid] = ls; __syncthreads();
    if (tid < 64) atomicAdd(&stats[tid], red[tid] + red[tid + 64] + red[tid + 128] + red[tid + 192]);
    __syncthreads();
    red[tid] = lq; __syncthreads();
    if (tid < 64) atomicAdd(&stats[64 + tid], red[tid] + red[tid + 64] + red[tid + 128] + red[tid + 192]);
}

// ---------------------------------------------------------------------------
__global__ void k_bnfin(const float* __restrict__ stats, const float* __restrict__ g,
                        const float* __restrict__ be, float* __restrict__ coef, float invN) {
    int c = threadIdx.x;
    float m = stats[c] * invN;
    float var = stats[64 + c] * invN - m * m;
    float a = g[c] * rsqrtf(var + EPS);
    coef[c] = a;
    coef[64 + c] = be[c] - m * a;
}

// ---------------------------------------------------------------------------
// Pre-transform (linear commute): per node i,
//   x1 = relu(bn1(h1_i));  y_i = x1@W2l;  z_i = x1@W2r + b2.
// Pure streaming MFMA; outputs staged in wave-private LDS -> full-line stores.
#define LROW 72  // LDS row stride in shorts

__global__ __launch_bounds__(256) void k_dense_pre(
    const unsigned short* __restrict__ h1b, const float* __restrict__ coef1,
    const float* __restrict__ W2l, const float* __restrict__ b2,
    const float* __restrict__ W2r,
    unsigned short* __restrict__ y, unsigned short* __restrict__ z, int n) {
    __shared__ unsigned short lds_w[16 * 64 * 8];                 // 16 KB
    __shared__ __align__(16) unsigned short lds_y[4][16 * LROW];  // per-wave y tile
    __shared__ __align__(16) unsigned short lds_z[4][16 * LROW];  // per-wave z tile
    int tid = threadIdx.x, w = tid >> 6, l = tid & 63, ln = l & 15, kg = l >> 4;

    // Stage W2l frags in slots 0..7, W2r in slots 8..15.
    // K=64: frag = (k>>5)*4 + (c>>4); lane = ((k>>3)&3)*16 + (c&15); j = k&7.
    for (int idx = tid; idx < 4096; idx += 256) {
        int k = idx >> 6, c = idx & 63;
        int lane = ((k >> 3) & 3) * 16 + (c & 15);
        int fbase = ((k >> 5) * 4 + (c >> 4)) * 64 + lane;
        lds_w[fbase * 8 + (k & 7)] = f2bf(W2l[idx]);
        lds_w[(8 * 64 + fbase) * 8 + (k & 7)] = f2bf(W2r[idx]);
    }
    __syncthreads();

    float bb[4];
#pragma unroll
    for (int cs = 0; cs < 4; ++cs) bb[cs] = b2[cs * 16 + ln];
    float c1a[16], c1b[16];
#pragma unroll
    for (int j = 0; j < 8; ++j) {
        c1a[j]     = coef1[kg * 8 + j];       c1b[j]     = coef1[64 + kg * 8 + j];
        c1a[8 + j] = coef1[32 + kg * 8 + j];  c1b[8 + j] = coef1[96 + kg * 8 + j];
    }

    unsigned short* Ys = lds_y[w];
    unsigned short* Zs = lds_z[w];
    const bf16x8* wfrag = (const bf16x8*)lds_w;
    int nt = (n + 15) >> 4;
    int stride = gridDim.x * 4;

#define LOADH(T, A)                                                          \
    {                                                                        \
        int row_ = ((T) << 4) + ln;                                          \
        int rr_ = (row_ < n) ? row_ : (n - 1);                               \
        const unsigned short* xr_ = h1b + (size_t)rr_ * 64 + kg * 8;         \
        A##0 = *(const bf16x8*)xr_;                                          \
        A##1 = *(const bf16x8*)(xr_ + 32);                                   \
    }

#define PROCESSH(T, A)                                                       \
    {                                                                        \
        bf16x8 u0_, u1_;                                                     \
        _Pragma("unroll")                                                    \
        for (int j = 0; j < 8; ++j) {                                        \
            float f0_ = bf2f((unsigned short)A##0[j]);                       \
            float f1_ = bf2f((unsigned short)A##1[j]);                       \
            u0_[j] = (short)f2bf(fmaxf(0.f, fmaf(f0_, c1a[j], c1b[j])));     \
            u1_[j] = (short)f2bf(fmaxf(0.f, fmaf(f1_, c1a[8 + j], c1b[8 + j]))); \
        }                                                                    \
        f32x4 ya_[4], za_[4];                                                \
        _Pragma("unroll")                                                    \
        for (int cs = 0; cs < 4; ++cs) {                                     \
            ya_[cs] = (f32x4){0.f, 0.f, 0.f, 0.f};                           \
            za_[cs] = (f32x4){0.f, 0.f, 0.f, 0.f};                           \
        }                                                                    \
        _Pragma("unroll")                                                    \
        for (int cs = 0; cs < 4; ++cs) {                                     \
            ya_[cs] = __builtin_amdgcn_mfma_f32_16x16x32_bf16(u0_, wfrag[(0 * 4 + cs) * 64 + l], ya_[cs], 0, 0, 0);  \
            ya_[cs] = __builtin_amdgcn_mfma_f32_16x16x32_bf16(u1_, wfrag[(1 * 4 + cs) * 64 + l], ya_[cs], 0, 0, 0);  \
            za_[cs] = __builtin_amdgcn_mfma_f32_16x16x32_bf16(u0_, wfrag[(8 + cs) * 64 + l], za_[cs], 0, 0, 0);      \
            za_[cs] = __builtin_amdgcn_mfma_f32_16x16x32_bf16(u1_, wfrag[(12 + cs) * 64 + l], za_[cs], 0, 0, 0);     \
        }                                                                    \
        _Pragma("unroll")                                                    \
        for (int cs = 0; cs < 4; ++cs) {                                     \
            _Pragma("unroll")                                                \
            for (int r = 0; r < 4; ++r) {                                    \
                Ys[(kg * 4 + r) * LROW + cs * 16 + ln] = f2bf(ya_[cs][r]);   \
                Zs[(kg * 4 + r) * LROW + cs * 16 + ln] = f2bf(za_[cs][r] + bb[cs]); \
            }                                                                \
        }                                                                    \
        asm volatile("s_waitcnt lgkmcnt(0)" ::: "memory");                   \
        int base_ = (T) << 4;                                                \
        int orow_ = l >> 2, oc_ = (l & 3) * 16;                              \
        if (base_ + orow_ < n) {                                             \
            const bf16x8* yp_ = (const bf16x8*)(Ys + orow_ * LROW + oc_);    \
            const bf16x8* zp_ = (const bf16x8*)(Zs + orow_ * LROW + oc_);    \
            bf16x8* yd_ = (bf16x8*)(y + (size_t)(base_ + orow_) * 64 + oc_); \
            bf16x8* zd_ = (bf16x8*)(z + (size_t)(base_ + orow_) * 64 + oc_); \
            yd_[0] = yp_[0]; yd_[1] = yp_[1];                                \
            zd_[0] = zp_[0]; zd_[1] = zp_[1];                                \
        }                                                                    \
        asm volatile("s_waitcnt lgkmcnt(0)" ::: "memory");                   \
    }

    bf16x8 P0, P1, Q0, Q1;
    int t = blockIdx.x * 4 + w;
    if (t < nt) {
        LOADH(t, P);
        while (t < nt) {
            int t1 = t + stride;
            if (t1 < nt) LOADH(t1, Q);
            PROCESSH(t, P);
            int t2 = t1 + stride;
            if (t2 < nt) LOADH(t2, P);
            if (t1 < nt) PROCESSH(t1, Q);
            t = t2;
        }
    }
#undef LOADH
#undef PROCESSH
}

// ---------------------------------------------------------------------------
// Gather + combine: h2_i = mean_j y[src_j] + z_i (z holds +b2), in place on z.
// 16-LANE GROUPS: each wave processes 4 nodes concurrently (4 independent
// dependency chains -> 4x memory-level parallelism vs wave-per-node).
// Lane lg covers channels 4*lg..4*lg+3 (one ushort4 = 8B; group row read is
// still a single 128B transaction). BN2 stats fused.
__global__ __launch_bounds__(256) void k_gather2b(
    const unsigned short* __restrict__ y, const int* __restrict__ rowptr,
    const int* __restrict__ csr, unsigned short* zh2,
    float* __restrict__ stats, int n) {
    int tid = threadIdx.x;
    int lg = tid & 15;                         // lane-in-group
    int gid0 = blockIdx.x * 16 + (tid >> 4);   // global group id
    int gstep = gridDim.x * 16;
    float ls0 = 0.f, ls1 = 0.f, ls2 = 0.f, ls3 = 0.f;
    float lq0 = 0.f, lq1 = 0.f, lq2 = 0.f, lq3 = 0.f;

    for (int i = gid0; i < n; i += gstep) {
        int r0 = rowptr[i], r1 = rowptr[i + 1];
        float s0 = 0.f, s1 = 0.f, s2 = 0.f, s3 = 0.f;
        int j = r0;
        for (; j + 1 < r1; j += 2) {
            int a = csr[j], b = csr[j + 1];
            ushort4 va = *(const ushort4*)(y + (size_t)a * 64 + lg * 4);
            ushort4 vb = *(const ushort4*)(y + (size_t)b * 64 + lg * 4);
            s0 += bf2f(va.x) + bf2f(vb.x);
            s1 += bf2f(va.y) + bf2f(vb.y);
            s2 += bf2f(va.z) + bf2f(vb.z);
            s3 += bf2f(va.w) + bf2f(vb.w);
        }
        if (j < r1) {
            ushort4 va = *(const ushort4*)(y + (size_t)csr[j] * 64 + lg * 4);
            s0 += bf2f(va.x); s1 += bf2f(va.y); s2 += bf2f(va.z); s3 += bf2f(va.w);
        }
        float inv = 1.f / fmaxf((float)(r1 - r0), 1.f);
        ushort4 z4 = *(const ushort4*)(zh2 + (size_t)i * 64 + lg * 4);
        float h0 = fmaf(s0, inv, bf2f(z4.x));
        float h1 = fmaf(s1, inv, bf2f(z4.y));
        float h2 = fmaf(s2, inv, bf2f(z4.z));
        float h3 = fmaf(s3, inv, bf2f(z4.w));
        ushort4 hb;
        hb.x = f2bf(h0); hb.y = f2bf(h1); hb.z = f2bf(h2); hb.w = f2bf(h3);
        *(ushort4*)(zh2 + (size_t)i * 64 + lg * 4) = hb;
        float f0 = bf2f(hb.x), f1 = bf2f(hb.y), f2 = bf2f(hb.z), f3 = bf2f(hb.w);
        ls0 += f0; ls1 += f1; ls2 += f2; ls3 += f3;
        lq0 += f0 * f0; lq1 += f1 * f1; lq2 += f2 * f2; lq3 += f3 * f3;
    }

    // combine the 4 groups of each wave (lanes l, l^16, l^32, l^48 share chans)
#pragma unroll
    for (int o = 16; o <= 32; o <<= 1) {
        ls0 += __shfl_xor(ls0, o, 64); ls1 += __shfl_xor(ls1, o, 64);
        ls2 += __shfl_xor(ls2, o, 64); ls3 += __shfl_xor(ls3, o, 64);
        lq0 += __shfl_xor(lq0, o, 64); lq1 += __shfl_xor(lq1, o, 64);
        lq2 += __shfl_xor(lq2, o, 64); lq3 += __shfl_xor(lq3, o, 64);
    }
    __shared__ float red[2][4][64];
    int w = tid >> 6;
    if ((tid & 63) < 16) {
        red[0][w][lg * 4 + 0] = ls0; red[0][w][lg * 4 + 1] = ls1;
        red[0][w][lg * 4 + 2] = ls2; red[0][w][lg * 4 + 3] = ls3;
        red[1][w][lg * 4 + 0] = lq0; red[1][w][lg * 4 + 1] = lq1;
        red[1][w][lg * 4 + 2] = lq2; red[1][w][lg * 4 + 3] = lq3;
    }
    __syncthreads();
    if (tid < 64) {
        atomicAdd(&stats[tid], red[0][0][tid] + red[0][1][tid] + red[0][2][tid] + red[0][3][tid]);
        atomicAdd(&stats[64 + tid], red[1][0][tid] + red[1][1][tid] + red[1][2][tid] + red[1][3][tid]);
    }
}

// ---------------------------------------------------------------------------
// Finalize: x2 = relu(bn2(h2)) + relu(bn1(h1)); t = x2.W3l; v = x2.W3r.
__global__ __launch_bounds__(256) void k_finalize(
    const unsigned short* __restrict__ h2b, const unsigned short* __restrict__ h1b,
    const float* __restrict__ coef1, const float* __restrict__ coef2,
    const float* __restrict__ W3l, const float* __restrict__ W3r,
    float* __restrict__ tb, float* __restrict__ vb, int n) {
    int tid = threadIdx.x, c = tid & 63, w = tid >> 6;
    int i0 = (blockIdx.x * 4 + w) * 8;
    if (i0 >= n) return;
    float a1 = coef1[c], b1 = coef1[64 + c];
    float a2 = coef2[c], b2 = coef2[64 + c];
    float wl = W3l[c], wr = W3r[c];
    float tv[8], vv[8];
#pragma unroll
    for (int q = 0; q < 8; ++q) {
        int i = i0 + q; int ic = (i < n) ? i : (n - 1);
        float h1v = bf2f(h1b[(size_t)ic * 64 + c]);
        float h2v = bf2f(h2b[(size_t)ic * 64 + c]);
        float x1v = fmaxf(0.f, fmaf(h1v, a1, b1));
        float x2v = fmaxf(0.f, fmaf(h2v, a2, b2)) + x1v;
        tv[q] = x2v * wl; vv[q] = x2v * wr;
    }
#pragma unroll
    for (int q = 0; q < 8; ++q) {
        float t = tv[q], v = vv[q];
#pragma unroll
        for (int o = 32; o > 0; o >>= 1) {
            t += __shfl_xor(t, o, 64);
            v += __shfl_xor(v, o, 64);
        }
        if (c == 0 && i0 + q < n) { tb[i0 + q] = t; vb[i0 + q] = v; }
    }
}

// ---------------------------------------------------------------------------
__global__ void k_gather3(const float* __restrict__ tb, const float* __restrict__ vb,
                          const int* __restrict__ rowptr, const int* __restrict__ csr,
                          const float* __restrict__ b3, float* __restrict__ out, int n) {
    int i = blockIdx.x * blockDim.x + threadIdx.x;
    if (i >= n) return;
    int r0 = rowptr[i], r1 = rowptr[i + 1];
    float s = 0.f;
    int j = r0;
    for (; j + 3 < r1; j += 4)
        s += tb[csr[j]] + tb[csr[j + 1]] + tb[csr[j + 2]] + tb[csr[j + 3]];
    for (; j < r1; ++j) s += tb[csr[j]];
    float inv = 1.f / fmaxf((float)(r1 - r0), 1.f);
    out[i] = fmaf(s, inv, b3[0] + vb[i]);
}

// ---------------------------------------------------------------------------
// Workspace (4B units, N=500k, E=1.25M; cap 256 MiB = 67,108,864 units):
//   h1b 32N + y 32N + zh2 32N + R 2N + rowptr N+1 + csr E + small
//   = ~50.8M units = 203 MB (safe)
extern "C" void kernel_launch(void* const* d_in, const int* in_sizes, int n_in,
                              void* d_out, int out_size, void* d_ws, size_t ws_size,
                              hipStream_t stream) {
    const float* x   = (const float*)d_in[0];
    const int*   ei  = (const int*)d_in[1];
    const float* W1l = (const float*)d_in[2];
    const float* b1  = (const float*)d_in[3];
    const float* W1r = (const float*)d_in[4];
    const float* g1  = (const float*)d_in[5];
    const float* be1 = (const float*)d_in[6];
    const float* W2l = (const float*)d_in[7];
    const float* b2  = (const float*)d_in[8];
    const float* W2r = (const float*)d_in[9];
    const float* g2  = (const float*)d_in[10];
    const float* be2 = (const float*)d_in[11];
    const float* W3l = (const float*)d_in[12];
    const float* b3  = (const float*)d_in[13];
    const float* W3r = (const float*)d_in[14];

    int N = in_sizes[0] / 2;
    int E = in_sizes[1] / 2;

    float* ws   = (float*)d_ws;
    size_t nn   = (size_t)N;
    unsigned short* h1b = (unsigned short*)ws;             // 32N units
    unsigned short* y   = (unsigned short*)(ws + 32 * nn); // 32N units
    unsigned short* zh2 = (unsigned short*)(ws + 64 * nn); // 32N units (z -> h2)
    float* R     = ws + 96 * nn;           // 2N time-shared region
    int*   cursor = (int*)R;               //   phase 1: CSR build (N+1 ints)
    float* agg1   = R;                     //   phase 2: layer-1 agg (2N f32)
    float* tb     = R;                     //   phase 3: layer-3 t (N f32)
    float* vb     = R + nn;                //   phase 3: layer-3 v (N f32)
    int*   rowptr = (int*)(ws + 98 * nn);  // N+1 (doubles as histogram cnt)
    int*   csr    = rowptr + (N + 1);      // E
    int*   bsums  = csr + E;               // 2048
    float* stats  = (float*)(bsums + 2048);// 256: s1,q1 | s2,q2
    float* coef   = stats + 256;           // 256: a1,b1 | a2,b2
    int*   flag   = (int*)(coef + 256);    // 64 (padded)

    hipMemsetAsync(rowptr, 0, (size_t)(N + 1) * sizeof(int), stream);
    hipMemsetAsync(stats, 0, 256 * sizeof(float), stream);

    k_detect<<<1, 1, 0, stream>>>(ei, flag);

    int ge = (E + 255) / 256;
    int nb = (N + 1023) / 1024;
    k_hist<<<ge, 256, 0, stream>>>(ei, flag, E, rowptr);
    k_scanA<<<nb, 256, 0, stream>>>(rowptr, N, bsums);
    k_scanB<<<1, 256, 0, stream>>>(bsums, nb, rowptr, N);
    k_scanC<<<nb, 256, 0, stream>>>(rowptr, N, bsums, cursor);
    k_fill<<<ge, 256, 0, stream>>>(ei, flag, E, cursor, csr);
    // cursor dead; R becomes agg1

    k_gather1<<<(N + 255) / 256, 256, 0, stream>>>(x, rowptr, csr, agg1, N);
    k_dense1<<<1024, 256, 0, stream>>>(x, agg1, W1l, b1, W1r, h1b, stats, N);
    k_bnfin<<<1, 64, 0, stream>>>(stats, g1, be1, coef, 1.0f / (float)N);
    // agg1 dead after dense1

    k_dense_pre<<<2048, 256, 0, stream>>>(h1b, coef, W2l, b2, W2r, y, zh2, N);
    k_gather2b<<<2048, 256, 0, stream>>>(y, rowptr, csr, zh2, stats + 128, N);
    k_bnfin<<<1, 64, 0, stream>>>(stats + 128, g2, be2, coef + 128, 1.0f / (float)N);

    // R becomes tb/vb
    k_finalize<<<(N + 31) / 32, 256, 0, stream>>>(zh2, h1b, coef, coef + 128,
                                                  W3l, W3r, tb, vb, N);
    k_gather3<<<(N + 255) / 256, 256, 0, stream>>>(tb, vb, rowptr, csr, b3, (float*)d_out, N);
}

// Round 10
// 485.445 us; speedup vs baseline: 1.6976x; 1.0198x over previous
//
#include <hip/hip_runtime.h>

#define EPS 1e-5f

typedef __attribute__((ext_vector_type(8))) short bf16x8;
typedef __attribute__((ext_vector_type(4))) float f32x4;

__device__ __forceinline__ unsigned short f2bf(float f) {
    unsigned u = __float_as_uint(f);
    u += 0x7fffu + ((u >> 16) & 1u);
    return (unsigned short)(u >> 16);
}
__device__ __forceinline__ float bf2f(unsigned short s) {
    return __uint_as_float(((unsigned)s) << 16);
}

// ---------------------------------------------------------------------------
// Edge-index dtype detection: JAX may emit int32 (x64 disabled) or int64.
__global__ void k_detect(const int* __restrict__ ei, int* __restrict__ flag) {
    if (blockIdx.x == 0 && threadIdx.x == 0) {
        int is64 = 1;
        for (int k = 0; k < 16; ++k) is64 &= (ei[2 * k + 1] == 0) ? 1 : 0;
        *flag = is64;
    }
}

// ---------------------------------------------------------------------------
// CSR build: histogram -> exclusive scan (3 kernels) -> fill
__global__ void k_hist(const int* __restrict__ ei, const int* __restrict__ flag,
                       int E, int* __restrict__ cnt) {
    int e = blockIdx.x * blockDim.x + threadIdx.x;
    if (e >= E) return;
    int d = (*flag) ? (int)((const long long*)ei)[E + e] : ei[E + e];
    atomicAdd(&cnt[d], 1);
}

__device__ __forceinline__ int block_incl_scan(int v, int tid, int* total) {
    __shared__ int wsum[4];
    __shared__ int tot;
#pragma unroll
    for (int o = 1; o < 64; o <<= 1) {
        int u = __shfl_up(v, o, 64);
        if ((tid & 63) >= o) v += u;
    }
    if ((tid & 63) == 63) wsum[tid >> 6] = v;
    __syncthreads();
    int w = tid >> 6, add = 0;
    if (w > 0) add += wsum[0];
    if (w > 1) add += wsum[1];
    if (w > 2) add += wsum[2];
    v += add;
    if (tid == 255) tot = v;
    __syncthreads();
    *total = tot;
    __syncthreads();
    return v;
}

__global__ __launch_bounds__(256) void k_scanA(const int* __restrict__ cnt, int n,
                                               int* __restrict__ bsums) {
    int tid = threadIdx.x;
    int idx = blockIdx.x * 1024 + tid * 4;
    int s = 0;
#pragma unroll
    for (int k = 0; k < 4; ++k) { int i = idx + k; if (i < n) s += cnt[i]; }
#pragma unroll
    for (int o = 32; o > 0; o >>= 1) s += __shfl_xor(s, o, 64);
    __shared__ int ws[4];
    if ((tid & 63) == 0) ws[tid >> 6] = s;
    __syncthreads();
    if (tid == 0) bsums[blockIdx.x] = ws[0] + ws[1] + ws[2] + ws[3];
}

__global__ __launch_bounds__(256) void k_scanB(int* __restrict__ bsums, int nb,
                                               int* __restrict__ rowptr, int N) {
    int tid = threadIdx.x;
    __shared__ int sh_carry;
    if (tid == 0) sh_carry = 0;
    __syncthreads();
    int niter = (nb + 255) / 256;
    for (int it = 0; it < niter; ++it) {
        int i = it * 256 + tid;
        int v = (i < nb) ? bsums[i] : 0;
        int tot;
        int inc = block_incl_scan(v, tid, &tot);
        int carry = sh_carry;
        if (i < nb) bsums[i] = carry + inc - v;
        __syncthreads();
        if (tid == 0) sh_carry = carry + tot;
        __syncthreads();
    }
    if (tid == 0) rowptr[N] = sh_carry;
}

__global__ __launch_bounds__(256) void k_scanC(int* __restrict__ cnt_rowptr, int n,
                                               const int* __restrict__ bsums,
                                               int* __restrict__ cursor) {
    int tid = threadIdx.x;
    int idx = blockIdx.x * 1024 + tid * 4;
    int v[4]; int s = 0;
#pragma unroll
    for (int k = 0; k < 4; ++k) { int i = idx + k; v[k] = (i < n) ? cnt_rowptr[i] : 0; s += v[k]; }
    int tot;
    int inc = block_incl_scan(s, tid, &tot);
    int off = bsums[blockIdx.x] + inc - s;
#pragma unroll
    for (int k = 0; k < 4; ++k) {
        int i = idx + k;
        if (i < n) { cnt_rowptr[i] = off; cursor[i] = off; off += v[k]; }
    }
}

__global__ void k_fill(const int* __restrict__ ei, const int* __restrict__ flag, int E,
                       int* __restrict__ cursor, int* __restrict__ csr) {
    int e = blockIdx.x * blockDim.x + threadIdx.x;
    if (e >= E) return;
    int s, d;
    if (*flag) {
        s = (int)((const long long*)ei)[e];
        d = (int)((const long long*)ei)[E + e];
    } else {
        s = ei[e]; d = ei[E + e];
    }
    int pos = atomicAdd(&cursor[d], 1);
    csr[pos] = s;
}

// ---------------------------------------------------------------------------
__global__ void k_gather1(const float* __restrict__ x, const int* __restrict__ rowptr,
                          const int* __restrict__ csr, float* __restrict__ agg1, int n) {
    int i = blockIdx.x * blockDim.x + threadIdx.x;
    if (i >= n) return;
    int r0 = rowptr[i], r1 = rowptr[i + 1];
    float s0 = 0.f, s1 = 0.f;
    for (int j = r0; j < r1; ++j) {
        float2 v = ((const float2*)x)[csr[j]];
        s0 += v.x; s1 += v.y;
    }
    float inv = 1.f / fmaxf((float)(r1 - r0), 1.f);
    agg1[2 * i] = s0 * inv;
    agg1[2 * i + 1] = s1 * inv;
}

// ---------------------------------------------------------------------------
// Layer-1 dense (K=2): h1 = agg1@W1l + b1 + x@W1r -> bf16 store.
// BN stats accumulated on the TRUNCATED value (self-consistent with readers).
__global__ __launch_bounds__(256) void k_dense1(
    const float* __restrict__ x, const float* __restrict__ agg1,
    const float* __restrict__ W1l, const float* __restrict__ b1,
    const float* __restrict__ W1r,
    unsigned short* __restrict__ h1b, float* __restrict__ stats, int n) {
    int tid = threadIdx.x, c = tid & 63, w = tid >> 6;
    float wl0 = W1l[c], wl1 = W1l[64 + c];
    float wr0 = W1r[c], wr1 = W1r[64 + c];
    float bb = b1[c];
    float ls = 0.f, lq = 0.f;
    for (int i = blockIdx.x * 4 + w; i < n; i += gridDim.x * 4) {
        float a0 = agg1[2 * i], a1 = agg1[2 * i + 1];
        float x0 = x[2 * i], x1v = x[2 * i + 1];
        float h = fmaf(a0, wl0, fmaf(a1, wl1, fmaf(x0, wr0, fmaf(x1v, wr1, bb))));
        unsigned short hb = f2bf(h);
        h1b[(size_t)i * 64 + c] = hb;
        float hf = bf2f(hb);
        ls += hf; lq += hf * hf;
    }
    __shared__ float red[256];
    red[tid] = ls; __syncthreads();
    if (tid < 64) atomicAdd(&stats[tid], red[tid] + red[tid + 64] + red[tid + 128] + red[tid + 192]);
    __syncthreads();
    red[tid] = lq; __syncthreads();
    if (tid < 64) atomicAdd(&stats[64 + tid], red[tid] + red[tid + 64] + red[tid + 128] + red[tid + 192]);
}

// ---------------------------------------------------------------------------
__global__ void k_bnfin(const float* __restrict__ stats, const float* __restrict__ g,
                        const float* __restrict__ be, float* __restrict__ coef, float invN) {
    int c = threadIdx.x;
    float m = stats[c] * invN;
    float var = stats[64 + c] * invN - m * m;
    float a = g[c] * rsqrtf(var + EPS);
    coef[c] = a;
    coef[64 + c] = be[c] - m * a;
}

// ---------------------------------------------------------------------------
// Pre-transform (linear commute): per node i,
//   x1 = relu(bn1(h1_i));  y_i = x1@W2l;  z_i = x1@W2r + b2.
// Pure streaming MFMA; outputs staged in wave-private LDS -> full-line stores.
#define LROW 72  // LDS row stride in shorts

__global__ __launch_bounds__(256) void k_dense_pre(
    const unsigned short* __restrict__ h1b, const float* __restrict__ coef1,
    const float* __restrict__ W2l, const float* __restrict__ b2,
    const float* __restrict__ W2r,
    unsigned short* __restrict__ y, unsigned short* __restrict__ z, int n) {
    __shared__ unsigned short lds_w[16 * 64 * 8];                 // 16 KB
    __shared__ __align__(16) unsigned short lds_y[4][16 * LROW];  // per-wave y tile
    __shared__ __align__(16) unsigned short lds_z[4][16 * LROW];  // per-wave z tile
    int tid = threadIdx.x, w = tid >> 6, l = tid & 63, ln = l & 15, kg = l >> 4;

    // Stage W2l frags in slots 0..7, W2r in slots 8..15.
    // K=64: frag = (k>>5)*4 + (c>>4); lane = ((k>>3)&3)*16 + (c&15); j = k&7.
    for (int idx = tid; idx < 4096; idx += 256) {
        int k = idx >> 6, c = idx & 63;
        int lane = ((k >> 3) & 3) * 16 + (c & 15);
        int fbase = ((k >> 5) * 4 + (c >> 4)) * 64 + lane;
        lds_w[fbase * 8 + (k & 7)] = f2bf(W2l[idx]);
        lds_w[(8 * 64 + fbase) * 8 + (k & 7)] = f2bf(W2r[idx]);
    }
    __syncthreads();

    float bb[4];
#pragma unroll
    for (int cs = 0; cs < 4; ++cs) bb[cs] = b2[cs * 16 + ln];
    float c1a[16], c1b[16];
#pragma unroll
    for (int j = 0; j < 8; ++j) {
        c1a[j]     = coef1[kg * 8 + j];       c1b[j]     = coef1[64 + kg * 8 + j];
        c1a[8 + j] = coef1[32 + kg * 8 + j];  c1b[8 + j] = coef1[96 + kg * 8 + j];
    }

    unsigned short* Ys = lds_y[w];
    unsigned short* Zs = lds_z[w];
    const bf16x8* wfrag = (const bf16x8*)lds_w;
    int nt = (n + 15) >> 4;
    int stride = gridDim.x * 4;

#define LOADH(T, A)                                                          \
    {                                                                        \
        int row_ = ((T) << 4) + ln;                                          \
        int rr_ = (row_ < n) ? row_ : (n - 1);                               \
        const unsigned short* xr_ = h1b + (size_t)rr_ * 64 + kg * 8;         \
        A##0 = *(const bf16x8*)xr_;                                          \
        A##1 = *(const bf16x8*)(xr_ + 32);                                   \
    }

#define PROCESSH(T, A)                                                       \
    {                                                                        \
        bf16x8 u0_, u1_;                                                     \
        _Pragma("unroll")                                                    \
        for (int j = 0; j < 8; ++j) {                                        \
            float f0_ = bf2f((unsigned short)A##0[j]);                       \
            float f1_ = bf2f((unsigned short)A##1[j]);                       \
            u0_[j] = (short)f2bf(fmaxf(0.f, fmaf(f0_, c1a[j], c1b[j])));     \
            u1_[j] = (short)f2bf(fmaxf(0.f, fmaf(f1_, c1a[8 + j], c1b[8 + j]))); \
        }                                                                    \
        f32x4 ya_[4], za_[4];                                                \
        _Pragma("unroll")                                                    \
        for (int cs = 0; cs < 4; ++cs) {                                     \
            ya_[cs] = (f32x4){0.f, 0.f, 0.f, 0.f};                           \
            za_[cs] = (f32x4){0.f, 0.f, 0.f, 0.f};                           \
        }                                                                    \
        _Pragma("unroll")                                                    \
        for (int cs = 0; cs < 4; ++cs) {                                     \
            ya_[cs] = __builtin_amdgcn_mfma_f32_16x16x32_bf16(u0_, wfrag[(0 * 4 + cs) * 64 + l], ya_[cs], 0, 0, 0);  \
            ya_[cs] = __builtin_amdgcn_mfma_f32_16x16x32_bf16(u1_, wfrag[(1 * 4 + cs) * 64 + l], ya_[cs], 0, 0, 0);  \
            za_[cs] = __builtin_amdgcn_mfma_f32_16x16x32_bf16(u0_, wfrag[(8 + cs) * 64 + l], za_[cs], 0, 0, 0);      \
            za_[cs] = __builtin_amdgcn_mfma_f32_16x16x32_bf16(u1_, wfrag[(12 + cs) * 64 + l], za_[cs], 0, 0, 0);     \
        }                                                                    \
        _Pragma("unroll")                                                    \
        for (int cs = 0; cs < 4; ++cs) {                                     \
            _Pragma("unroll")                                                \
            for (int r = 0; r < 4; ++r) {                                    \
                Ys[(kg * 4 + r) * LROW + cs * 16 + ln] = f2bf(ya_[cs][r]);   \
                Zs[(kg * 4 + r) * LROW + cs * 16 + ln] = f2bf(za_[cs][r] + bb[cs]); \
            }                                                                \
        }                                                                    \
        asm volatile("s_waitcnt lgkmcnt(0)" ::: "memory");                   \
        int base_ = (T) << 4;                                                \
        int orow_ = l >> 2, oc_ = (l & 3) * 16;                              \
        if (base_ + orow_ < n) {                                             \
            const bf16x8* yp_ = (const bf16x8*)(Ys + orow_ * LROW + oc_);    \
            const bf16x8* zp_ = (const bf16x8*)(Zs + orow_ * LROW + oc_);    \
            bf16x8* yd_ = (bf16x8*)(y + (size_t)(base_ + orow_) * 64 + oc_); \
            bf16x8* zd_ = (bf16x8*)(z + (size_t)(base_ + orow_) * 64 + oc_); \
            yd_[0] = yp_[0]; yd_[1] = yp_[1];                                \
            zd_[0] = zp_[0]; zd_[1] = zp_[1];                                \
        }                                                                    \
        asm volatile("s_waitcnt lgkmcnt(0)" ::: "memory");                   \
    }

    bf16x8 P0, P1, Q0, Q1;
    int t = blockIdx.x * 4 + w;
    if (t < nt) {
        LOADH(t, P);
        while (t < nt) {
            int t1 = t + stride;
            if (t1 < nt) LOADH(t1, Q);
            PROCESSH(t, P);
            int t2 = t1 + stride;
            if (t2 < nt) LOADH(t2, P);
            if (t1 < nt) PROCESSH(t1, Q);
            t = t2;
        }
    }
#undef LOADH
#undef PROCESSH
}

// ---------------------------------------------------------------------------
// Gather + combine: h2_i = mean_j y[src_j] + z_i (z holds +b2), in place on z.
// 8-LANE GROUPS: each wave processes 8 nodes concurrently (8 independent
// dependency chains). Lane lg covers channels 8*lg..8*lg+7 via one 16B load;
// a group's row read is one 128B segment; one wave-level load instruction
// fetches 8 independent rows (1KB). BN2 stats fused.
__global__ __launch_bounds__(256) void k_gather2b(
    const unsigned short* __restrict__ y, const int* __restrict__ rowptr,
    const int* __restrict__ csr, unsigned short* zh2,
    float* __restrict__ stats, int n) {
    int tid = threadIdx.x;
    int lg = tid & 7;                          // lane-in-group
    int gid0 = blockIdx.x * 32 + (tid >> 3);   // global group id (32 groups/block)
    int gstep = gridDim.x * 32;
    float ls[8] = {0.f, 0.f, 0.f, 0.f, 0.f, 0.f, 0.f, 0.f};
    float lq[8] = {0.f, 0.f, 0.f, 0.f, 0.f, 0.f, 0.f, 0.f};

    for (int i = gid0; i < n; i += gstep) {
        int r0 = rowptr[i], r1 = rowptr[i + 1];
        float s[8] = {0.f, 0.f, 0.f, 0.f, 0.f, 0.f, 0.f, 0.f};
        int j = r0;
        for (; j + 1 < r1; j += 2) {
            int a = csr[j], b = csr[j + 1];
            bf16x8 va = *(const bf16x8*)(y + (size_t)a * 64 + lg * 8);
            bf16x8 vb = *(const bf16x8*)(y + (size_t)b * 64 + lg * 8);
#pragma unroll
            for (int k = 0; k < 8; ++k)
                s[k] += bf2f((unsigned short)va[k]) + bf2f((unsigned short)vb[k]);
        }
        if (j < r1) {
            bf16x8 va = *(const bf16x8*)(y + (size_t)csr[j] * 64 + lg * 8);
#pragma unroll
            for (int k = 0; k < 8; ++k) s[k] += bf2f((unsigned short)va[k]);
        }
        float inv = 1.f / fmaxf((float)(r1 - r0), 1.f);
        bf16x8 z8 = *(const bf16x8*)(zh2 + (size_t)i * 64 + lg * 8);
        bf16x8 hb;
#pragma unroll
        for (int k = 0; k < 8; ++k) {
            float h = fmaf(s[k], inv, bf2f((unsigned short)z8[k]));
            unsigned short b = f2bf(h);
            hb[k] = (short)b;
            float hf = bf2f(b);
            ls[k] += hf; lq[k] += hf * hf;
        }
        *(bf16x8*)(zh2 + (size_t)i * 64 + lg * 8) = hb;
    }

    // lanes sharing lg (l, l^8, l^16, ..., l^56) hold the same 8 channels
#pragma unroll
    for (int k = 0; k < 8; ++k) {
        ls[k] += __shfl_xor(ls[k], 8, 64);
        ls[k] += __shfl_xor(ls[k], 16, 64);
        ls[k] += __shfl_xor(ls[k], 32, 64);
        lq[k] += __shfl_xor(lq[k], 8, 64);
        lq[k] += __shfl_xor(lq[k], 16, 64);
        lq[k] += __shfl_xor(lq[k], 32, 64);
    }
    __shared__ float red[2][4][64];
    int w = tid >> 6;
    if ((tid & 63) < 8) {
#pragma unroll
        for (int k = 0; k < 8; ++k) {
            red[0][w][lg * 8 + k] = ls[k];
            red[1][w][lg * 8 + k] = lq[k];
        }
    }
    __syncthreads();
    if (tid < 64) {
        atomicAdd(&stats[tid], red[0][0][tid] + red[0][1][tid] + red[0][2][tid] + red[0][3][tid]);
        atomicAdd(&stats[64 + tid], red[1][0][tid] + red[1][1][tid] + red[1][2][tid] + red[1][3][tid]);
    }
}

// ---------------------------------------------------------------------------
// Finalize: x2 = relu(bn2(h2)) + relu(bn1(h1)); t = x2.W3l; v = x2.W3r.
__global__ __launch_bounds__(256) void k_finalize(
    const unsigned short* __restrict__ h2b, const unsigned short* __restrict__ h1b,
    const float* __restrict__ coef1, const float* __restrict__ coef2,
    const float* __restrict__ W3l, const float* __restrict__ W3r,
    float* __restrict__ tb, float* __restrict__ vb, int n) {
    int tid = threadIdx.x, c = tid & 63, w = tid >> 6;
    int i0 = (blockIdx.x * 4 + w) * 8;
    if (i0 >= n) return;
    float a1 = coef1[c], b1 = coef1[64 + c];
    float a2 = coef2[c], b2 = coef2[64 + c];
    float wl = W3l[c], wr = W3r[c];
    float tv[8], vv[8];
#pragma unroll
    for (int q = 0; q < 8; ++q) {
        int i = i0 + q; int ic = (i < n) ? i : (n - 1);
        float h1v = bf2f(h1b[(size_t)ic * 64 + c]);
        float h2v = bf2f(h2b[(size_t)ic * 64 + c]);
        float x1v = fmaxf(0.f, fmaf(h1v, a1, b1));
        float x2v = fmaxf(0.f, fmaf(h2v, a2, b2)) + x1v;
        tv[q] = x2v * wl; vv[q] = x2v * wr;
    }
#pragma unroll
    for (int q = 0; q < 8; ++q) {
        float t = tv[q], v = vv[q];
#pragma unroll
        for (int o = 32; o > 0; o >>= 1) {
            t += __shfl_xor(t, o, 64);
            v += __shfl_xor(v, o, 64);
        }
        if (c == 0 && i0 + q < n) { tb[i0 + q] = t; vb[i0 + q] = v; }
    }
}

// ---------------------------------------------------------------------------
__global__ void k_gather3(const float* __restrict__ tb, const float* __restrict__ vb,
                          const int* __restrict__ rowptr, const int* __restrict__ csr,
                          const float* __restrict__ b3, float* __restrict__ out, int n) {
    int i = blockIdx.x * blockDim.x + threadIdx.x;
    if (i >= n) return;
    int r0 = rowptr[i], r1 = rowptr[i + 1];
    float s = 0.f;
    int j = r0;
    for (; j + 3 < r1; j += 4)
        s += tb[csr[j]] + tb[csr[j + 1]] + tb[csr[j + 2]] + tb[csr[j + 3]];
    for (; j < r1; ++j) s += tb[csr[j]];
    float inv = 1.f / fmaxf((float)(r1 - r0), 1.f);
    out[i] = fmaf(s, inv, b3[0] + vb[i]);
}

// ---------------------------------------------------------------------------
// Workspace (4B units, N=500k, E=1.25M; cap 256 MiB = 67,108,864 units):
//   h1b 32N + y 32N + zh2 32N + R 2N + rowptr N+1 + csr E + small
//   = ~50.8M units = 203 MB (safe)
extern "C" void kernel_launch(void* const* d_in, const int* in_sizes, int n_in,
                              void* d_out, int out_size, void* d_ws, size_t ws_size,
                              hipStream_t stream) {
    const float* x   = (const float*)d_in[0];
    const int*   ei  = (const int*)d_in[1];
    const float* W1l = (const float*)d_in[2];
    const float* b1  = (const float*)d_in[3];
    const float* W1r = (const float*)d_in[4];
    const float* g1  = (const float*)d_in[5];
    const float* be1 = (const float*)d_in[6];
    const float* W2l = (const float*)d_in[7];
    const float* b2  = (const float*)d_in[8];
    const float* W2r = (const float*)d_in[9];
    const float* g2  = (const float*)d_in[10];
    const float* be2 = (const float*)d_in[11];
    const float* W3l = (const float*)d_in[12];
    const float* b3  = (const float*)d_in[13];
    const float* W3r = (const float*)d_in[14];

    int N = in_sizes[0] / 2;
    int E = in_sizes[1] / 2;

    float* ws   = (float*)d_ws;
    size_t nn   = (size_t)N;
    unsigned short* h1b = (unsigned short*)ws;             // 32N units
    unsigned short* y   = (unsigned short*)(ws + 32 * nn); // 32N units
    unsigned short* zh2 = (unsigned short*)(ws + 64 * nn); // 32N units (z -> h2)
    float* R     = ws + 96 * nn;           // 2N time-shared region
    int*   cursor = (int*)R;               //   phase 1: CSR build (N+1 ints)
    float* agg1   = R;                     //   phase 2: layer-1 agg (2N f32)
    float* tb     = R;                     //   phase 3: layer-3 t (N f32)
    float* vb     = R + nn;                //   phase 3: layer-3 v (N f32)
    int*   rowptr = (int*)(ws + 98 * nn);  // N+1 (doubles as histogram cnt)
    int*   csr    = rowptr + (N + 1);      // E
    int*   bsums  = csr + E;               // 2048
    float* stats  = (float*)(bsums + 2048);// 256: s1,q1 | s2,q2
    float* coef   = stats + 256;           // 256: a1,b1 | a2,b2
    int*   flag   = (int*)(coef + 256);    // 64 (padded)

    hipMemsetAsync(rowptr, 0, (size_t)(N + 1) * sizeof(int), stream);
    hipMemsetAsync(stats, 0, 256 * sizeof(float), stream);

    k_detect<<<1, 1, 0, stream>>>(ei, flag);

    int ge = (E + 255) / 256;
    int nb = (N + 1023) / 1024;
    k_hist<<<ge, 256, 0, stream>>>(ei, flag, E, rowptr);
    k_scanA<<<nb, 256, 0, stream>>>(rowptr, N, bsums);
    k_scanB<<<1, 256, 0, stream>>>(bsums, nb, rowptr, N);
    k_scanC<<<nb, 256, 0, stream>>>(rowptr, N, bsums, cursor);
    k_fill<<<ge, 256, 0, stream>>>(ei, flag, E, cursor, csr);
    // cursor dead; R becomes agg1

    k_gather1<<<(N + 255) / 256, 256, 0, stream>>>(x, rowptr, csr, agg1, N);
    k_dense1<<<1024, 256, 0, stream>>>(x, agg1, W1l, b1, W1r, h1b, stats, N);
    k_bnfin<<<1, 64, 0, stream>>>(stats, g1, be1, coef, 1.0f / (float)N);
    // agg1 dead after dense1

    k_dense_pre<<<2048, 256, 0, stream>>>(h1b, coef, W2l, b2, W2r, y, zh2, N);
    k_gather2b<<<2048, 256, 0, stream>>>(y, rowptr, csr, zh2, stats + 128, N);
    k_bnfin<<<1, 64, 0, stream>>>(stats + 128, g2, be2, coef + 128, 1.0f / (float)N);

    // R becomes tb/vb
    k_finalize<<<(N + 31) / 32, 256, 0, stream>>>(zh2, h1b, coef, coef + 128,
                                                  W3l, W3r, tb, vb, N);
    k_gather3<<<(N + 255) / 256, 256, 0, stream>>>(tb, vb, rowptr, csr, b3, (float*)d_out, N);
}